// Round 3
// baseline (680.055 us; speedup 1.0000x reference)
//
#include <hip/hip_runtime.h>
#include <hip/hip_bf16.h>

typedef __bf16 bf16_t;
typedef __bf16 bf16x8 __attribute__((ext_vector_type(8)));
typedef __bf16 bf16x4 __attribute__((ext_vector_type(4)));
typedef float  f32x4  __attribute__((ext_vector_type(4)));
typedef __attribute__((address_space(3))) unsigned as3u32;
typedef __attribute__((address_space(1))) unsigned as1u32;

#define Bdim 4
#define Sdim 2048
#define Ddim 1024
#define Edim 2048
#define CH 64   // scan chunks
#define CL 32   // chunk length (CH*CL == Sdim)

__device__ __forceinline__ void gload_lds16(const void* g, void* l) {
  __builtin_amdgcn_global_load_lds((const as1u32*)g, (as3u32*)l, 16, 0, 0);
}

__device__ __forceinline__ float sigmoidf_(float x) {
  return 1.f / (1.f + __expf(-x));
}

// ---------------- weight fp32 -> bf16 ----------------
__global__ __launch_bounds__(256)
void cvt_bf16(const float* __restrict__ s, bf16_t* __restrict__ d, int n) {
  int i = blockIdx.x * 256 + threadIdx.x;
  if (i < n) d[i] = (bf16_t)s[i];
}

// ---------------- scan scalars ----------------
__global__ __launch_bounds__(256)
void prep_scalars(const float* __restrict__ ld, const float* __restrict__ Am,
                  const float* __restrict__ Bm, float* __restrict__ aexp,
                  float* __restrict__ Ce) {
  int e = blockIdx.x * 256 + threadIdx.x;
  if (e >= Edim) return;
  float d = ld[e];
  float sp = (d > 20.f) ? d : log1pf(expf(d));
  aexp[e] = expf(-sp);
  float s = 0.f;
  #pragma unroll
  for (int n = 0; n < 16; ++n) s += Am[e * 16 + n] * Bm[e * 16 + n];
  Ce[e] = s;
}

// ---------------- layernorm ----------------
__global__ __launch_bounds__(256)
void ln_kernel(const float* __restrict__ x, const float* __restrict__ g,
               const float* __restrict__ b, bf16_t* __restrict__ out) {
  const int row = blockIdx.x;
  const int tid = threadIdx.x;
  const float4 v = ((const float4*)(x + (size_t)row * Ddim))[tid];
  float s  = v.x + v.y + v.z + v.w;
  float ss = v.x * v.x + v.y * v.y + v.z * v.z + v.w * v.w;
  #pragma unroll
  for (int o = 32; o > 0; o >>= 1) { s += __shfl_down(s, o); ss += __shfl_down(ss, o); }
  __shared__ float sh[8];
  const int wv = tid >> 6, lane = tid & 63;
  if (lane == 0) { sh[wv] = s; sh[4 + wv] = ss; }
  __syncthreads();
  s  = sh[0] + sh[1] + sh[2] + sh[3];
  ss = sh[4] + sh[5] + sh[6] + sh[7];
  const float mean = s * (1.f / Ddim);
  const float var  = ss * (1.f / Ddim) - mean * mean;
  const float rstd = rsqrtf(var + 1e-5f);
  const float4 gv = ((const float4*)g)[tid];
  const float4 bv = ((const float4*)b)[tid];
  bf16x4 o;
  o[0] = (bf16_t)((v.x - mean) * rstd * gv.x + bv.x);
  o[1] = (bf16_t)((v.y - mean) * rstd * gv.y + bv.y);
  o[2] = (bf16_t)((v.z - mean) * rstd * gv.z + bv.z);
  o[3] = (bf16_t)((v.w - mean) * rstd * gv.w + bv.w);
  *(bf16x4*)(out + (size_t)row * Ddim + tid * 4) = o;
}

// ============ GEMM common: 128x128 tile, BK=32, XOR-swizzled LDS ============
// LDS chunk swizzle: global k-chunk q of row r is stored at LDS chunk q^((r>>1)&3).
// Staging lanes stay contiguous (global_load_lds constraint); every 16-lane
// ds_read_b128 phase then covers 8 bank-groups x 2 lanes = conflict-free (m136).
#define BM 128
#define BN 128
#define BK 32

// MODE 0: Cb = bf16(acc+bias);  MODE 1: Cf = acc+bias+R (fp32)
template<int MODE>
__global__ __launch_bounds__(256)
void gemm_bt(const bf16_t* __restrict__ A, const bf16_t* __restrict__ Bw,
             const float* __restrict__ bias, const float* __restrict__ R,
             bf16_t* __restrict__ Cb, float* __restrict__ Cf,
             int M, int N, int K) {
  __shared__ __align__(16) bf16_t As[BM * BK];
  __shared__ __align__(16) bf16_t Bs[BN * BK];

  const int tid  = threadIdx.x;
  const int lane = tid & 63;
  const int wv   = tid >> 6;
  const int m0   = blockIdx.y * BM;
  const int n0   = blockIdx.x * BN;

  const int wr = (wv >> 1) * 64;
  const int wc = (wv & 1) * 64;
  const int tq = lane >> 4;
  const int tr = lane & 15;

  f32x4 acc[4][4] = {};

  const int row0 = tid >> 2;
  const int kp0  = (((tid & 3) ^ ((row0 >> 1) & 3)) * 8);  // swizzled global k-offset
  const int row1 = row0 + 64;                               // same (row>>1)&3 parity class
  const size_t aBase = (size_t)m0 * K;
  const size_t bBase = (size_t)n0 * K;
  char* AsB = (char*)As;
  char* BsB = (char*)Bs;
  const int ldsOff0 = wv * 1024;
  const int ldsOff1 = 4096 + wv * 1024;

  // read-side swizzled chunk offset (lane-constant)
  const int sk = (tq ^ ((tr >> 1) & 3)) * 8;

  for (int k0 = 0; k0 < K; k0 += BK) {
    __syncthreads();
    gload_lds16(A  + aBase + (size_t)row0 * K + k0 + kp0, AsB + ldsOff0);
    gload_lds16(A  + aBase + (size_t)row1 * K + k0 + kp0, AsB + ldsOff1);
    gload_lds16(Bw + bBase + (size_t)row0 * K + k0 + kp0, BsB + ldsOff0);
    gload_lds16(Bw + bBase + (size_t)row1 * K + k0 + kp0, BsB + ldsOff1);
    __syncthreads();

    bf16x8 af[4], bfr[4];
    #pragma unroll
    for (int i = 0; i < 4; ++i)
      af[i] = *(const bf16x8*)&As[(wr + i * 16 + tr) * BK + sk];
    #pragma unroll
    for (int j = 0; j < 4; ++j)
      bfr[j] = *(const bf16x8*)&Bs[(wc + j * 16 + tr) * BK + sk];
    #pragma unroll
    for (int i = 0; i < 4; ++i)
      #pragma unroll
      for (int j = 0; j < 4; ++j)
        acc[i][j] = __builtin_amdgcn_mfma_f32_16x16x32_bf16(af[i], bfr[j], acc[i][j], 0, 0, 0);
  }

  #pragma unroll
  for (int i = 0; i < 4; ++i) {
    #pragma unroll
    for (int j = 0; j < 4; ++j) {
      const int col = n0 + wc + j * 16 + tr;
      const float bv = bias[col];
      #pragma unroll
      for (int r = 0; r < 4; ++r) {
        const int rowg = m0 + wr + i * 16 + tq * 4 + r;
        const size_t idx = (size_t)rowg * N + col;
        const float v = acc[i][j][r] + bv;
        if (MODE == 1) Cf[idx] = v + R[idx];
        else           Cb[idx] = (bf16_t)v;
      }
    }
  }
}

// Dual-B GEMM: c = A@Wc^T + bc, d = A@Wd^T + bd, u = c*sigmoid(d) -> U (bf16)
// A staged once; 32 MFMA per k-iter vs 6 staging loads.
__global__ __launch_bounds__(256)
void gemm_cd(const bf16_t* __restrict__ A, const bf16_t* __restrict__ Wc,
             const bf16_t* __restrict__ Wd, const float* __restrict__ bc,
             const float* __restrict__ bd, bf16_t* __restrict__ U,
             int M, int N, int K) {
  __shared__ __align__(16) bf16_t As[BM * BK];
  __shared__ __align__(16) bf16_t Bs1[BN * BK];
  __shared__ __align__(16) bf16_t Bs2[BN * BK];

  const int tid  = threadIdx.x;
  const int lane = tid & 63;
  const int wv   = tid >> 6;
  const int m0   = blockIdx.y * BM;
  const int n0   = blockIdx.x * BN;

  const int wr = (wv >> 1) * 64;
  const int wc = (wv & 1) * 64;
  const int tq = lane >> 4;
  const int tr = lane & 15;

  f32x4 accC[4][4] = {};
  f32x4 accD[4][4] = {};

  const int row0 = tid >> 2;
  const int kp0  = (((tid & 3) ^ ((row0 >> 1) & 3)) * 8);
  const int row1 = row0 + 64;
  const size_t aBase = (size_t)m0 * K;
  const size_t bBase = (size_t)n0 * K;
  char* AsB = (char*)As;
  char* B1B = (char*)Bs1;
  char* B2B = (char*)Bs2;
  const int ldsOff0 = wv * 1024;
  const int ldsOff1 = 4096 + wv * 1024;

  const int sk = (tq ^ ((tr >> 1) & 3)) * 8;

  for (int k0 = 0; k0 < K; k0 += BK) {
    __syncthreads();
    gload_lds16(A  + aBase + (size_t)row0 * K + k0 + kp0, AsB + ldsOff0);
    gload_lds16(A  + aBase + (size_t)row1 * K + k0 + kp0, AsB + ldsOff1);
    gload_lds16(Wc + bBase + (size_t)row0 * K + k0 + kp0, B1B + ldsOff0);
    gload_lds16(Wc + bBase + (size_t)row1 * K + k0 + kp0, B1B + ldsOff1);
    gload_lds16(Wd + bBase + (size_t)row0 * K + k0 + kp0, B2B + ldsOff0);
    gload_lds16(Wd + bBase + (size_t)row1 * K + k0 + kp0, B2B + ldsOff1);
    __syncthreads();

    bf16x8 af[4], bc_[4], bd_[4];
    #pragma unroll
    for (int i = 0; i < 4; ++i)
      af[i] = *(const bf16x8*)&As[(wr + i * 16 + tr) * BK + sk];
    #pragma unroll
    for (int j = 0; j < 4; ++j) {
      bc_[j] = *(const bf16x8*)&Bs1[(wc + j * 16 + tr) * BK + sk];
      bd_[j] = *(const bf16x8*)&Bs2[(wc + j * 16 + tr) * BK + sk];
    }
    #pragma unroll
    for (int i = 0; i < 4; ++i)
      #pragma unroll
      for (int j = 0; j < 4; ++j) {
        accC[i][j] = __builtin_amdgcn_mfma_f32_16x16x32_bf16(af[i], bc_[j], accC[i][j], 0, 0, 0);
        accD[i][j] = __builtin_amdgcn_mfma_f32_16x16x32_bf16(af[i], bd_[j], accD[i][j], 0, 0, 0);
      }
  }

  #pragma unroll
  for (int i = 0; i < 4; ++i) {
    #pragma unroll
    for (int j = 0; j < 4; ++j) {
      const int col = n0 + wc + j * 16 + tr;
      const float bcv = bc[col];
      const float bdv = bd[col];
      #pragma unroll
      for (int r = 0; r < 4; ++r) {
        const int rowg = m0 + wr + i * 16 + tq * 4 + r;
        const size_t idx = (size_t)rowg * N + col;
        const float cv = accC[i][j][r] + bcv;
        const float dv = accD[i][j][r] + bdv;
        U[idx] = (bf16_t)(cv * sigmoidf_(dv));
      }
    }
  }
}

// ---------------- causal depthwise conv (K=4) + silu ----------------
__global__ __launch_bounds__(256)
void conv_silu(const bf16_t* __restrict__ xpg, const float* __restrict__ cw,
               const float* __restrict__ cb, bf16_t* __restrict__ xc) {
  const int e  = blockIdx.y * 256 + threadIdx.x;
  const int b  = blockIdx.x >> 9;
  const int s0 = (blockIdx.x & 511) * 4;
  const float w0 = cw[e * 4 + 0], w1 = cw[e * 4 + 1], w2 = cw[e * 4 + 2], w3 = cw[e * 4 + 3];
  const float bias = cb[e];
  float xv[7];
  #pragma unroll
  for (int j = 0; j < 7; ++j) {
    const int s = s0 - 3 + j;
    xv[j] = (s >= 0) ? (float)xpg[(size_t)(b * Sdim + s) * (2 * Edim) + e] : 0.f;
  }
  #pragma unroll
  for (int t = 0; t < 4; ++t) {
    float a = fmaf(w0, xv[t], fmaf(w1, xv[t + 1], fmaf(w2, xv[t + 2], fmaf(w3, xv[t + 3], bias))));
    float y = a * sigmoidf_(a);
    xc[(size_t)(b * Sdim + s0 + t) * Edim + e] = (bf16_t)y;
  }
}

// ---------------- chunked parallel scan ----------------
__global__ __launch_bounds__(256)
void scan_part1(const bf16_t* __restrict__ u, const float* __restrict__ aexp,
                float* __restrict__ zloc) {
  const int c    = blockIdx.x;
  const int b    = blockIdx.y >> 3;
  const int eblk = blockIdx.y & 7;
  const int e    = eblk * 256 + threadIdx.x;
  const float a  = aexp[e];
  const bf16_t* up = u + ((size_t)(b * Sdim + c * CL)) * Edim + e;
  float z = 0.f;
  #pragma unroll
  for (int t = 0; t < CL; ++t) z = fmaf(a, z, (float)up[(size_t)t * Edim]);
  zloc[((size_t)b * CH + c) * Edim + e] = z;
}

__global__ __launch_bounds__(256)
void scan_part2(const float* __restrict__ aexp, float* __restrict__ zloc) {
  const int idx = blockIdx.x * 256 + threadIdx.x;
  const int b = idx >> 11, e = idx & (Edim - 1);
  float a  = aexp[e];
  float aL = a * a;
  aL = aL * aL; aL = aL * aL; aL = aL * aL; aL = aL * aL;  // a^32
  float* zp = zloc + (size_t)b * CH * Edim + e;
  float pref = 0.f;
  #pragma unroll 4
  for (int c = 0; c < CH; ++c) {
    const float loc = zp[(size_t)c * Edim];
    zp[(size_t)c * Edim] = pref;
    pref = fmaf(aL, pref, loc);
  }
}

__global__ __launch_bounds__(256)
void scan_part3(const bf16_t* __restrict__ u, const bf16_t* __restrict__ xpg,
                const float* __restrict__ aexp, const float* __restrict__ Ce,
                const float* __restrict__ zloc, bf16_t* __restrict__ xg) {
  const int c    = blockIdx.x;
  const int b    = blockIdx.y >> 3;
  const int eblk = blockIdx.y & 7;
  const int e    = eblk * 256 + threadIdx.x;
  const float a = aexp[e], C = Ce[e];
  float z = zloc[((size_t)b * CH + c) * Edim + e];
  const bf16_t* up = u   + ((size_t)(b * Sdim + c * CL)) * Edim + e;
  const bf16_t* gp = xpg + ((size_t)(b * Sdim + c * CL)) * (2 * Edim) + Edim + e;
  bf16_t*       op = xg  + ((size_t)(b * Sdim + c * CL)) * Edim + e;
  #pragma unroll 8
  for (int t = 0; t < CL; ++t) {
    z = fmaf(a, z, (float)up[(size_t)t * Edim]);
    const float gv = (float)gp[(size_t)t * (2 * Edim)];
    op[(size_t)t * Edim] = (bf16_t)(C * z * sigmoidf_(gv));
  }
}

extern "C" void kernel_launch(void* const* d_in, const int* in_sizes, int n_in,
                              void* d_out, int out_size, void* d_ws, size_t ws_size,
                              hipStream_t stream) {
  const float* x         = (const float*)d_in[0];
  const float* ln_g      = (const float*)d_in[1];
  const float* ln_b      = (const float*)d_in[2];
  const float* W_in      = (const float*)d_in[3];
  const float* b_in      = (const float*)d_in[4];
  const float* conv_w    = (const float*)d_in[5];
  const float* conv_b    = (const float*)d_in[6];
  const float* Am        = (const float*)d_in[7];
  const float* Bm        = (const float*)d_in[8];
  const float* W_c       = (const float*)d_in[9];
  const float* b_c       = (const float*)d_in[10];
  const float* W_d       = (const float*)d_in[11];
  const float* b_d       = (const float*)d_in[12];
  const float* log_delta = (const float*)d_in[13];
  const float* W_out     = (const float*)d_in[14];
  const float* b_out     = (const float*)d_in[15];
  float* out = (float*)d_out;

  const size_t MiB = 1024 * 1024;
  char* w = (char*)d_ws;
  bf16_t* wWin  = (bf16_t*)(w + 0);           //  8 MiB
  bf16_t* wWc   = (bf16_t*)(w + 8 * MiB);     //  8 MiB
  bf16_t* wWd   = (bf16_t*)(w + 16 * MiB);    //  8 MiB
  bf16_t* wWout = (bf16_t*)(w + 24 * MiB);    //  4 MiB
  float*  aexp  = (float*) (w + 28 * MiB);
  float*  Ce    = (float*) (w + 28 * MiB + 16384);
  float*  zloc  = (float*) (w + 28 * MiB + 65536);  // 2 MiB
  bf16_t* xln   = (bf16_t*)(w + 31 * MiB);    // 16 MiB
  bf16_t* xpg   = (bf16_t*)(w + 47 * MiB);    // 64 MiB
  bf16_t* xc    = (bf16_t*)(w + 111 * MiB);   // 32 MiB
  bf16_t* ubuf  = (bf16_t*)(w + 143 * MiB);   // 32 MiB (u)
  bf16_t* gbuf  = (bf16_t*)(w + 175 * MiB);   // 32 MiB (xg) -> ends 207 MiB

  const int M = Bdim * Sdim;  // 8192

  cvt_bf16<<<(2 * Edim * Ddim) / 256, 256, 0, stream>>>(W_in, wWin, 2 * Edim * Ddim);
  cvt_bf16<<<(Edim * Edim) / 256, 256, 0, stream>>>(W_c, wWc, Edim * Edim);
  cvt_bf16<<<(Edim * Edim) / 256, 256, 0, stream>>>(W_d, wWd, Edim * Edim);
  cvt_bf16<<<(Ddim * Edim) / 256, 256, 0, stream>>>(W_out, wWout, Ddim * Edim);
  prep_scalars<<<Edim / 256, 256, 0, stream>>>(log_delta, Am, Bm, aexp, Ce);

  ln_kernel<<<M, 256, 0, stream>>>(x, ln_g, ln_b, xln);

  // x_proj = x_ln @ W_in^T + b_in
  gemm_bt<0><<<dim3((2 * Edim) / BN, M / BM), 256, 0, stream>>>(
      xln, wWin, b_in, nullptr, xpg, nullptr, M, 2 * Edim, Ddim);

  conv_silu<<<dim3(Bdim * (Sdim / 4), Edim / 256), 256, 0, stream>>>(xpg, conv_w, conv_b, xc);

  // u = (xc@Wc^T+bc) * sigmoid(xc@Wd^T+bd)   (fused dual GEMM)
  gemm_cd<<<dim3(Edim / BN, M / BM), 256, 0, stream>>>(
      xc, wWc, wWd, b_c, b_d, ubuf, M, Edim, Edim);

  scan_part1<<<dim3(CH, Bdim * (Edim / 256)), 256, 0, stream>>>(ubuf, aexp, zloc);
  scan_part2<<<(Bdim * Edim) / 256, 256, 0, stream>>>(aexp, zloc);
  scan_part3<<<dim3(CH, Bdim * (Edim / 256)), 256, 0, stream>>>(ubuf, xpg, aexp, Ce, zloc, gbuf);

  // out = xg @ W_out^T + b_out + x
  gemm_bt<1><<<dim3(Ddim / BN, M / BM), 256, 0, stream>>>(
      gbuf, wWout, b_out, x, nullptr, out, M, Ddim, Edim);

  (void)in_sizes; (void)n_in; (void)out_size; (void)ws_size;
}

// Round 4
// 490.585 us; speedup vs baseline: 1.3862x; 1.3862x over previous
//
#include <hip/hip_runtime.h>
#include <hip/hip_bf16.h>

typedef __bf16 bf16_t;
typedef unsigned char u8;
typedef __bf16 bf16x8 __attribute__((ext_vector_type(8)));
typedef __bf16 bf16x4 __attribute__((ext_vector_type(4)));
typedef float  f32x4  __attribute__((ext_vector_type(4)));
typedef __attribute__((address_space(3))) unsigned as3u32;
typedef __attribute__((address_space(1))) unsigned as1u32;

#define Bdim 4
#define Sdim 2048
#define Ddim 1024
#define Edim 2048
#define CH 64
#define CL 32

#define WSCALE 32.0f   // weight fp8 pre-scale
#define XCSCALE 16.0f  // conv activation fp8 pre-scale

__device__ __forceinline__ void gload_lds16(const void* g, void* l) {
  __builtin_amdgcn_global_load_lds((const as1u32*)g, (as3u32*)l, 16, 0, 0);
}
__device__ __forceinline__ float sigmoidf_(float x) {
  return 1.f / (1.f + __expf(-x));
}
__device__ __forceinline__ int pk_fp8x4(float a, float b, float c, float d) {
  int p = __builtin_amdgcn_cvt_pk_fp8_f32(a, b, 0, 0);
  p = __builtin_amdgcn_cvt_pk_fp8_f32(c, d, p, 1);
  return p;
}

// ---------------- weight fp32 -> fp8 (scaled) ----------------
__global__ __launch_bounds__(256)
void cvt_fp8(const float* __restrict__ s, u8* __restrict__ d, int n, float scale) {
  int i = (blockIdx.x * 256 + threadIdx.x) * 4;
  if (i < n) {
    *(int*)(d + i) = pk_fp8x4(s[i] * scale, s[i + 1] * scale,
                              s[i + 2] * scale, s[i + 3] * scale);
  }
}

// ---------------- weight fp32 -> bf16 (W_out) ----------------
__global__ __launch_bounds__(256)
void cvt_bf16(const float* __restrict__ s, bf16_t* __restrict__ d, int n) {
  int i = blockIdx.x * 256 + threadIdx.x;
  if (i < n) d[i] = (bf16_t)s[i];
}

// ---------------- scan scalars ----------------
__global__ __launch_bounds__(256)
void prep_scalars(const float* __restrict__ ld, const float* __restrict__ Am,
                  const float* __restrict__ Bm, float* __restrict__ aexp,
                  float* __restrict__ Ce) {
  int e = blockIdx.x * 256 + threadIdx.x;
  if (e >= Edim) return;
  float d = ld[e];
  float sp = (d > 20.f) ? d : log1pf(expf(d));
  aexp[e] = expf(-sp);
  float s = 0.f;
  #pragma unroll
  for (int n = 0; n < 16; ++n) s += Am[e * 16 + n] * Bm[e * 16 + n];
  Ce[e] = s;
}

// ---------------- layernorm -> fp8 (scale 1) ----------------
__global__ __launch_bounds__(256)
void ln_kernel(const float* __restrict__ x, const float* __restrict__ g,
               const float* __restrict__ b, u8* __restrict__ out) {
  const int row = blockIdx.x;
  const int tid = threadIdx.x;
  const float4 v = ((const float4*)(x + (size_t)row * Ddim))[tid];
  float s  = v.x + v.y + v.z + v.w;
  float ss = v.x * v.x + v.y * v.y + v.z * v.z + v.w * v.w;
  #pragma unroll
  for (int o = 32; o > 0; o >>= 1) { s += __shfl_down(s, o); ss += __shfl_down(ss, o); }
  __shared__ float sh[8];
  const int wv = tid >> 6, lane = tid & 63;
  if (lane == 0) { sh[wv] = s; sh[4 + wv] = ss; }
  __syncthreads();
  s  = sh[0] + sh[1] + sh[2] + sh[3];
  ss = sh[4] + sh[5] + sh[6] + sh[7];
  const float mean = s * (1.f / Ddim);
  const float var  = ss * (1.f / Ddim) - mean * mean;
  const float rstd = rsqrtf(var + 1e-5f);
  const float4 gv = ((const float4*)g)[tid];
  const float4 bv = ((const float4*)b)[tid];
  *(int*)(out + (size_t)row * Ddim + tid * 4) =
      pk_fp8x4((v.x - mean) * rstd * gv.x + bv.x,
               (v.y - mean) * rstd * gv.y + bv.y,
               (v.z - mean) * rstd * gv.z + bv.z,
               (v.w - mean) * rstd * gv.w + bv.w);
}

// ============ fp8 GEMM_BT: 128x128 tile, BK=64 (bytes == bf16 BK=32 layout) ======
// acc = (A8 @ B8^T) * descale + bias.  MODE 0: Cb = bf16(v). MODE 2: Cb = bf16(X*sigmoid(v)).
// LDS 16B-chunk swizzle q ^= (row>>1)&3 (4 chunks/row); read side mirrors it.
#define BM 128
#define BN 128

template<int MODE>
__global__ __launch_bounds__(256)
void gemm_f8(const u8* __restrict__ A, const u8* __restrict__ Bw,
             const float* __restrict__ bias, const bf16_t* __restrict__ X,
             bf16_t* __restrict__ Cb, float descale, int M, int N, int K) {
  __shared__ __align__(16) u8 As[BM * 64];
  __shared__ __align__(16) u8 Bs[BN * 64];

  const int tid  = threadIdx.x;
  const int lane = tid & 63;
  const int wv   = tid >> 6;
  const int m0   = blockIdx.y * BM;
  const int n0   = blockIdx.x * BN;

  const int wr = (wv >> 1) * 64;
  const int wc = (wv & 1) * 64;
  const int tq = lane >> 4;
  const int tr = lane & 15;

  f32x4 acc[4][4] = {};

  const int row0 = tid >> 2;
  const int qs   = ((tid & 3) ^ ((row0 >> 1) & 3)) * 16;  // swizzled byte offset in row
  const int row1 = row0 + 64;                              // same swizzle class
  const size_t aBase = (size_t)m0 * K;
  const size_t bBase = (size_t)n0 * K;
  char* AsB = (char*)As;
  char* BsB = (char*)Bs;
  const int ldsOff0 = wv * 1024;
  const int ldsOff1 = 4096 + wv * 1024;

  const int sw = (tr >> 1) & 3;  // read-side chunk swizzle
  // frag byte address within tile: row*64 + ((kk*2 + (tq>>1)) ^ sw)*16 + (tq&1)*8
  const int fo0 = (((tq >> 1) ^ sw) * 16) + (tq & 1) * 8;          // kk=0
  const int fo1 = (((2 + (tq >> 1)) ^ sw) * 16) + (tq & 1) * 8;    // kk=1

  for (int k0 = 0; k0 < K; k0 += 64) {
    __syncthreads();
    gload_lds16(A  + aBase + (size_t)row0 * K + k0 + qs, AsB + ldsOff0);
    gload_lds16(A  + aBase + (size_t)row1 * K + k0 + qs, AsB + ldsOff1);
    gload_lds16(Bw + bBase + (size_t)row0 * K + k0 + qs, BsB + ldsOff0);
    gload_lds16(Bw + bBase + (size_t)row1 * K + k0 + qs, BsB + ldsOff1);
    __syncthreads();

    long aF[4][2], bF[4][2];
    #pragma unroll
    for (int i = 0; i < 4; ++i) {
      const int rb = (wr + i * 16 + tr) * 64;
      aF[i][0] = *(const long*)&As[rb + fo0];
      aF[i][1] = *(const long*)&As[rb + fo1];
    }
    #pragma unroll
    for (int j = 0; j < 4; ++j) {
      const int rb = (wc + j * 16 + tr) * 64;
      bF[j][0] = *(const long*)&Bs[rb + fo0];
      bF[j][1] = *(const long*)&Bs[rb + fo1];
    }
    #pragma unroll
    for (int i = 0; i < 4; ++i)
      #pragma unroll
      for (int j = 0; j < 4; ++j) {
        acc[i][j] = __builtin_amdgcn_mfma_f32_16x16x32_fp8_fp8(aF[i][0], bF[j][0], acc[i][j], 0, 0, 0);
        acc[i][j] = __builtin_amdgcn_mfma_f32_16x16x32_fp8_fp8(aF[i][1], bF[j][1], acc[i][j], 0, 0, 0);
      }
  }

  #pragma unroll
  for (int i = 0; i < 4; ++i) {
    #pragma unroll
    for (int j = 0; j < 4; ++j) {
      const int col = n0 + wc + j * 16 + tr;
      const float bv = bias[col];
      #pragma unroll
      for (int r = 0; r < 4; ++r) {
        const int rowg = m0 + wr + i * 16 + tq * 4 + r;
        const size_t idx = (size_t)rowg * N + col;
        const float v = acc[i][j][r] * descale + bv;
        if (MODE == 2) Cb[idx] = (bf16_t)((float)X[idx] * sigmoidf_(v));
        else           Cb[idx] = (bf16_t)v;
      }
    }
  }
}

// ============ bf16 GEMM_BT (out-projection): Cf = acc + bias + R ============
#define BK 32
__global__ __launch_bounds__(256)
void gemm_bt_res(const bf16_t* __restrict__ A, const bf16_t* __restrict__ Bw,
                 const float* __restrict__ bias, const float* __restrict__ R,
                 float* __restrict__ Cf, int M, int N, int K) {
  __shared__ __align__(16) bf16_t As[BM * BK];
  __shared__ __align__(16) bf16_t Bs[BN * BK];

  const int tid  = threadIdx.x;
  const int lane = tid & 63;
  const int wv   = tid >> 6;
  const int m0   = blockIdx.y * BM;
  const int n0   = blockIdx.x * BN;

  const int wr = (wv >> 1) * 64;
  const int wc = (wv & 1) * 64;
  const int tq = lane >> 4;
  const int tr = lane & 15;

  f32x4 acc[4][4] = {};

  const int row0 = tid >> 2;
  const int kp0  = (((tid & 3) ^ ((row0 >> 1) & 3)) * 8);
  const int row1 = row0 + 64;
  const size_t aBase = (size_t)m0 * K;
  const size_t bBase = (size_t)n0 * K;
  char* AsB = (char*)As;
  char* BsB = (char*)Bs;
  const int ldsOff0 = wv * 1024;
  const int ldsOff1 = 4096 + wv * 1024;
  const int sk = (tq ^ ((tr >> 1) & 3)) * 8;

  for (int k0 = 0; k0 < K; k0 += BK) {
    __syncthreads();
    gload_lds16(A  + aBase + (size_t)row0 * K + k0 + kp0, AsB + ldsOff0);
    gload_lds16(A  + aBase + (size_t)row1 * K + k0 + kp0, AsB + ldsOff1);
    gload_lds16(Bw + bBase + (size_t)row0 * K + k0 + kp0, BsB + ldsOff0);
    gload_lds16(Bw + bBase + (size_t)row1 * K + k0 + kp0, BsB + ldsOff1);
    __syncthreads();

    bf16x8 af[4], bfr[4];
    #pragma unroll
    for (int i = 0; i < 4; ++i)
      af[i] = *(const bf16x8*)&As[(wr + i * 16 + tr) * BK + sk];
    #pragma unroll
    for (int j = 0; j < 4; ++j)
      bfr[j] = *(const bf16x8*)&Bs[(wc + j * 16 + tr) * BK + sk];
    #pragma unroll
    for (int i = 0; i < 4; ++i)
      #pragma unroll
      for (int j = 0; j < 4; ++j)
        acc[i][j] = __builtin_amdgcn_mfma_f32_16x16x32_bf16(af[i], bfr[j], acc[i][j], 0, 0, 0);
  }

  #pragma unroll
  for (int i = 0; i < 4; ++i) {
    #pragma unroll
    for (int j = 0; j < 4; ++j) {
      const int col = n0 + wc + j * 16 + tr;
      const float bv = bias[col];
      #pragma unroll
      for (int r = 0; r < 4; ++r) {
        const int rowg = m0 + wr + i * 16 + tq * 4 + r;
        const size_t idx = (size_t)rowg * N + col;
        Cf[idx] = acc[i][j][r] + bv + R[idx];
      }
    }
  }
}

// ---------------- causal depthwise conv (K=4) + silu -> fp8 (scaled) ----------------
__global__ __launch_bounds__(256)
void conv_silu(const bf16_t* __restrict__ xpg, const float* __restrict__ cw,
               const float* __restrict__ cb, u8* __restrict__ xc) {
  const int e  = blockIdx.y * 256 + threadIdx.x;
  const int b  = blockIdx.x >> 9;
  const int s0 = (blockIdx.x & 511) * 4;
  const float w0 = cw[e * 4 + 0], w1 = cw[e * 4 + 1], w2 = cw[e * 4 + 2], w3 = cw[e * 4 + 3];
  const float bias = cb[e];
  float xv[7];
  #pragma unroll
  for (int j = 0; j < 7; ++j) {
    const int s = s0 - 3 + j;
    xv[j] = (s >= 0) ? (float)xpg[(size_t)(b * Sdim + s) * (2 * Edim) + e] : 0.f;
  }
  #pragma unroll
  for (int t = 0; t < 4; ++t) {
    float a = fmaf(w0, xv[t], fmaf(w1, xv[t + 1], fmaf(w2, xv[t + 2], fmaf(w3, xv[t + 3], bias))));
    float y = a * sigmoidf_(a) * XCSCALE;
    int p = __builtin_amdgcn_cvt_pk_fp8_f32(y, y, 0, 0);
    xc[(size_t)(b * Sdim + s0 + t) * Edim + e] = (u8)(p & 0xff);
  }
}

// ---------------- chunked parallel scan ----------------
__global__ __launch_bounds__(256)
void scan_part1(const bf16_t* __restrict__ u, const float* __restrict__ aexp,
                float* __restrict__ zloc) {
  const int c    = blockIdx.x;
  const int b    = blockIdx.y >> 3;
  const int eblk = blockIdx.y & 7;
  const int e    = eblk * 256 + threadIdx.x;
  const float a  = aexp[e];
  const bf16_t* up = u + ((size_t)(b * Sdim + c * CL)) * Edim + e;
  float z = 0.f;
  #pragma unroll
  for (int t = 0; t < CL; ++t) z = fmaf(a, z, (float)up[(size_t)t * Edim]);
  zloc[((size_t)b * CH + c) * Edim + e] = z;
}

__global__ __launch_bounds__(256)
void scan_part2(const float* __restrict__ aexp, float* __restrict__ zloc) {
  const int idx = blockIdx.x * 256 + threadIdx.x;
  const int b = idx >> 11, e = idx & (Edim - 1);
  float a  = aexp[e];
  float aL = a * a;
  aL = aL * aL; aL = aL * aL; aL = aL * aL; aL = aL * aL;  // a^32
  float* zp = zloc + (size_t)b * CH * Edim + e;
  float pref = 0.f;
  #pragma unroll 4
  for (int c = 0; c < CH; ++c) {
    const float loc = zp[(size_t)c * Edim];
    zp[(size_t)c * Edim] = pref;
    pref = fmaf(aL, pref, loc);
  }
}

__global__ __launch_bounds__(256)
void scan_part3(const bf16_t* __restrict__ u, const bf16_t* __restrict__ xpg,
                const float* __restrict__ aexp, const float* __restrict__ Ce,
                const float* __restrict__ zloc, bf16_t* __restrict__ xg) {
  const int c    = blockIdx.x;
  const int b    = blockIdx.y >> 3;
  const int eblk = blockIdx.y & 7;
  const int e    = eblk * 256 + threadIdx.x;
  const float a = aexp[e], C = Ce[e];
  float z = zloc[((size_t)b * CH + c) * Edim + e];
  const bf16_t* up = u   + ((size_t)(b * Sdim + c * CL)) * Edim + e;
  const bf16_t* gp = xpg + ((size_t)(b * Sdim + c * CL)) * (2 * Edim) + Edim + e;
  bf16_t*       op = xg  + ((size_t)(b * Sdim + c * CL)) * Edim + e;
  #pragma unroll 8
  for (int t = 0; t < CL; ++t) {
    z = fmaf(a, z, (float)up[(size_t)t * Edim]);
    const float gv = (float)gp[(size_t)t * (2 * Edim)];
    op[(size_t)t * Edim] = (bf16_t)(C * z * sigmoidf_(gv));
  }
}

extern "C" void kernel_launch(void* const* d_in, const int* in_sizes, int n_in,
                              void* d_out, int out_size, void* d_ws, size_t ws_size,
                              hipStream_t stream) {
  const float* x         = (const float*)d_in[0];
  const float* ln_g      = (const float*)d_in[1];
  const float* ln_b      = (const float*)d_in[2];
  const float* W_in      = (const float*)d_in[3];
  const float* b_in      = (const float*)d_in[4];
  const float* conv_w    = (const float*)d_in[5];
  const float* conv_b    = (const float*)d_in[6];
  const float* Am        = (const float*)d_in[7];
  const float* Bm        = (const float*)d_in[8];
  const float* W_c       = (const float*)d_in[9];
  const float* b_c       = (const float*)d_in[10];
  const float* W_d       = (const float*)d_in[11];
  const float* b_d       = (const float*)d_in[12];
  const float* log_delta = (const float*)d_in[13];
  const float* W_out     = (const float*)d_in[14];
  const float* b_out     = (const float*)d_in[15];
  float* out = (float*)d_out;

  const size_t MiB = 1024 * 1024;
  char* w = (char*)d_ws;
  u8*     wWin8 = (u8*)    (w + 0);            //  4 MiB (4096x1024)
  u8*     wWc8  = (u8*)    (w + 4 * MiB);      //  4 MiB
  u8*     wWd8  = (u8*)    (w + 8 * MiB);      //  4 MiB
  bf16_t* wWout = (bf16_t*)(w + 12 * MiB);     //  4 MiB (1024x2048 bf16)
  float*  aexp  = (float*) (w + 16 * MiB);
  float*  Ce    = (float*) (w + 16 * MiB + 16384);
  float*  zloc  = (float*) (w + 16 * MiB + 65536);  // 2 MiB
  u8*     xln8  = (u8*)    (w + 19 * MiB);     //  8 MiB (8192x1024)
  bf16_t* xpg   = (bf16_t*)(w + 27 * MiB);     // 64 MiB (8192x4096 bf16)
  u8*     xc8   = (u8*)    (w + 91 * MiB);     // 16 MiB (8192x2048)
  bf16_t* cbuf  = (bf16_t*)(w + 107 * MiB);    // 32 MiB (c)
  bf16_t* ubuf  = (bf16_t*)(w + 139 * MiB);    // 32 MiB (u)
  bf16_t* gbuf  = (bf16_t*)(w + 171 * MiB);    // 32 MiB (xg) -> 203 MiB

  const int M = Bdim * Sdim;  // 8192
  const float dsIn = 1.f / WSCALE;             // W_in: xln unscaled * W*32
  const float dsCD = 1.f / (WSCALE * XCSCALE); // Wc/Wd: xc*16 * W*32

  cvt_fp8<<<(2 * Edim * Ddim) / 1024, 256, 0, stream>>>(W_in, wWin8, 2 * Edim * Ddim, WSCALE);
  cvt_fp8<<<(Edim * Edim) / 1024, 256, 0, stream>>>(W_c, wWc8, Edim * Edim, WSCALE);
  cvt_fp8<<<(Edim * Edim) / 1024, 256, 0, stream>>>(W_d, wWd8, Edim * Edim, WSCALE);
  cvt_bf16<<<(Ddim * Edim) / 256, 256, 0, stream>>>(W_out, wWout, Ddim * Edim);
  prep_scalars<<<Edim / 256, 256, 0, stream>>>(log_delta, Am, Bm, aexp, Ce);

  ln_kernel<<<M, 256, 0, stream>>>(x, ln_g, ln_b, xln8);

  // x_proj = x_ln @ W_in^T + b_in  (fp8 -> bf16 xpg)
  gemm_f8<0><<<dim3((2 * Edim) / BN, M / BM), 256, 0, stream>>>(
      xln8, wWin8, b_in, nullptr, xpg, dsIn, M, 2 * Edim, Ddim);

  conv_silu<<<dim3(Bdim * (Sdim / 4), Edim / 256), 256, 0, stream>>>(xpg, conv_w, conv_b, xc8);

  // c = xc @ Wc^T + bc
  gemm_f8<0><<<dim3(Edim / BN, M / BM), 256, 0, stream>>>(
      xc8, wWc8, b_c, nullptr, cbuf, dsCD, M, Edim, Edim);
  // u = c * sigmoid(xc @ Wd^T + bd)
  gemm_f8<2><<<dim3(Edim / BN, M / BM), 256, 0, stream>>>(
      xc8, wWd8, b_d, cbuf, ubuf, dsCD, M, Edim, Edim);

  scan_part1<<<dim3(CH, Bdim * (Edim / 256)), 256, 0, stream>>>(ubuf, aexp, zloc);
  scan_part2<<<(Bdim * Edim) / 256, 256, 0, stream>>>(aexp, zloc);
  scan_part3<<<dim3(CH, Bdim * (Edim / 256)), 256, 0, stream>>>(ubuf, xpg, aexp, Ce, zloc, gbuf);

  // out = xg @ W_out^T + b_out + x  (bf16 GEMM, fp32 out)
  gemm_bt_res<<<dim3(Ddim / BN, M / BM), 256, 0, stream>>>(
      gbuf, wWout, b_out, x, out, M, Ddim, Edim);

  (void)in_sizes; (void)n_in; (void)out_size; (void)ws_size;
}

// Round 5
// 409.245 us; speedup vs baseline: 1.6617x; 1.1988x over previous
//
#include <hip/hip_runtime.h>
#include <hip/hip_bf16.h>

typedef __bf16 bf16_t;
typedef unsigned char u8;
typedef __bf16 bf16x8 __attribute__((ext_vector_type(8)));
typedef __bf16 bf16x4 __attribute__((ext_vector_type(4)));
typedef float  f32x4  __attribute__((ext_vector_type(4)));
typedef int    i32x4  __attribute__((ext_vector_type(4)));
typedef int    i32x8  __attribute__((ext_vector_type(8)));
typedef __attribute__((address_space(3))) unsigned as3u32;
typedef __attribute__((address_space(1))) unsigned as1u32;

#define Bdim 4
#define Sdim 2048
#define Ddim 1024
#define Edim 2048
#define CH 64
#define CL 32

#define WSCALE 32.0f   // weight fp8 pre-scale
#define XCSCALE 16.0f  // conv activation fp8 pre-scale

__device__ __forceinline__ void gload_lds16(const void* g, void* l) {
  __builtin_amdgcn_global_load_lds((const as1u32*)g, (as3u32*)l, 16, 0, 0);
}
__device__ __forceinline__ float sigmoidf_(float x) {
  return 1.f / (1.f + __expf(-x));
}
__device__ __forceinline__ int pk_fp8x4(float a, float b, float c, float d) {
  int p = __builtin_amdgcn_cvt_pk_fp8_f32(a, b, 0, 0);
  p = __builtin_amdgcn_cvt_pk_fp8_f32(c, d, p, 1);
  return p;
}

// ---------------- 3 weight arrays fp32 -> fp8 (all 4194304 elts, scale WSCALE) ----
__global__ __launch_bounds__(256)
void cvt_fp8_3(const float* __restrict__ s0, const float* __restrict__ s1,
               const float* __restrict__ s2, u8* __restrict__ d0,
               u8* __restrict__ d1, u8* __restrict__ d2) {
  const int seg = blockIdx.x >> 12;          // 4096 blocks per segment
  const int i   = ((blockIdx.x & 4095) * 256 + threadIdx.x) * 4;
  const float* s = (seg == 0) ? s0 : (seg == 1) ? s1 : s2;
  u8*          d = (seg == 0) ? d0 : (seg == 1) ? d1 : d2;
  *(int*)(d + i) = pk_fp8x4(s[i] * WSCALE, s[i + 1] * WSCALE,
                            s[i + 2] * WSCALE, s[i + 3] * WSCALE);
}

// ---------------- weight fp32 -> bf16 (W_out) ----------------
__global__ __launch_bounds__(256)
void cvt_bf16(const float* __restrict__ s, bf16_t* __restrict__ d, int n) {
  int i = blockIdx.x * 256 + threadIdx.x;
  if (i < n) d[i] = (bf16_t)s[i];
}

// ---------------- scan scalars ----------------
__global__ __launch_bounds__(256)
void prep_scalars(const float* __restrict__ ld, const float* __restrict__ Am,
                  const float* __restrict__ Bm, float* __restrict__ aexp,
                  float* __restrict__ Ce) {
  int e = blockIdx.x * 256 + threadIdx.x;
  if (e >= Edim) return;
  float d = ld[e];
  float sp = (d > 20.f) ? d : log1pf(expf(d));
  aexp[e] = expf(-sp);
  float s = 0.f;
  #pragma unroll
  for (int n = 0; n < 16; ++n) s += Am[e * 16 + n] * Bm[e * 16 + n];
  Ce[e] = s;
}

// ---------------- layernorm -> fp8 ----------------
__global__ __launch_bounds__(256)
void ln_kernel(const float* __restrict__ x, const float* __restrict__ g,
               const float* __restrict__ b, u8* __restrict__ out) {
  const int row = blockIdx.x;
  const int tid = threadIdx.x;
  const float4 v = ((const float4*)(x + (size_t)row * Ddim))[tid];
  float s  = v.x + v.y + v.z + v.w;
  float ss = v.x * v.x + v.y * v.y + v.z * v.z + v.w * v.w;
  #pragma unroll
  for (int o = 32; o > 0; o >>= 1) { s += __shfl_down(s, o); ss += __shfl_down(ss, o); }
  __shared__ float sh[8];
  const int wv = tid >> 6, lane = tid & 63;
  if (lane == 0) { sh[wv] = s; sh[4 + wv] = ss; }
  __syncthreads();
  s  = sh[0] + sh[1] + sh[2] + sh[3];
  ss = sh[4] + sh[5] + sh[6] + sh[7];
  const float mean = s * (1.f / Ddim);
  const float var  = ss * (1.f / Ddim) - mean * mean;
  const float rstd = rsqrtf(var + 1e-5f);
  const float4 gv = ((const float4*)g)[tid];
  const float4 bv = ((const float4*)b)[tid];
  *(int*)(out + (size_t)row * Ddim + tid * 4) =
      pk_fp8x4((v.x - mean) * rstd * gv.x + bv.x,
               (v.y - mean) * rstd * gv.y + bv.y,
               (v.z - mean) * rstd * gv.z + bv.z,
               (v.w - mean) * rstd * gv.w + bv.w);
}

// ============ MX fp8 GEMM_BT: 128x128 tile, BK=128, mfma_scale 16x16x128 =========
// acc = (A8 @ B8^T) * descale + bias (unit e8m0 scales = exact fp8 product).
// LDS: 16B chunk c of row r stored at position c ^ (r&7); frag read is
// 2x ds_read_b128 per operand row (read swizzle lane-constant: tr&7), 2-way = free.
// MODE 0: Cb = bf16(v). MODE 2: Cb = bf16(X*sigmoid(v)).
#define BM 128
#define BN 128

template<int MODE>
__global__ __launch_bounds__(256)
void gemm_mx(const u8* __restrict__ A, const u8* __restrict__ Bw,
             const float* __restrict__ bias, const bf16_t* __restrict__ X,
             bf16_t* __restrict__ Cb, float descale, int M, int N, int K) {
  __shared__ __align__(16) u8 As[BM * 128];   // 16 KB
  __shared__ __align__(16) u8 Bs[BN * 128];   // 16 KB

  const int tid  = threadIdx.x;
  const int lane = tid & 63;
  const int wv   = tid >> 6;
  const int m0   = blockIdx.y * BM;
  const int n0   = blockIdx.x * BN;

  const int wr = (wv >> 1) * 64;
  const int wc = (wv & 1) * 64;
  const int tq = lane >> 4;
  const int tr = lane & 15;

  f32x4 acc[4][4] = {};

  // staging: 1024 chunks of 16B per operand; instruction g covers positions
  // p = g*256 + tid; source chunk index = (p&7) ^ (row&7)  (XOR swizzle)
  size_t srcOff[4];
  int    ldsOff[4];
  #pragma unroll
  for (int g = 0; g < 4; ++g) {
    const int p   = g * 256 + tid;
    const int row = p >> 3;
    const int c   = (p & 7) ^ (row & 7);
    srcOff[g] = (size_t)row * K + c * 16;
    ldsOff[g] = g * 4096 + wv * 1024;
  }
  const size_t aBase = (size_t)m0 * K;
  const size_t bBase = (size_t)n0 * K;
  char* AsB = (char*)As;
  char* BsB = (char*)Bs;

  // frag read positions (byte offsets within a 128B row), lane-constant
  const int s7 = tr & 7;
  const int p0 = (((tq << 1)) ^ s7) * 16;
  const int p1 = (((tq << 1) | 1) ^ s7) * 16;

  for (int k0 = 0; k0 < K; k0 += 128) {
    __syncthreads();
    #pragma unroll
    for (int g = 0; g < 4; ++g)
      gload_lds16(A + aBase + srcOff[g] + k0, AsB + ldsOff[g]);
    #pragma unroll
    for (int g = 0; g < 4; ++g)
      gload_lds16(Bw + bBase + srcOff[g] + k0, BsB + ldsOff[g]);
    __syncthreads();

    i32x8 aF[4], bF[4];
    #pragma unroll
    for (int i = 0; i < 4; ++i) {
      const int rb = (wr + i * 16 + tr) * 128;
      const i32x4 lo = *(const i32x4*)&As[rb + p0];
      const i32x4 hi = *(const i32x4*)&As[rb + p1];
      aF[i] = __builtin_shufflevector(lo, hi, 0, 1, 2, 3, 4, 5, 6, 7);
    }
    #pragma unroll
    for (int j = 0; j < 4; ++j) {
      const int rb = (wc + j * 16 + tr) * 128;
      const i32x4 lo = *(const i32x4*)&Bs[rb + p0];
      const i32x4 hi = *(const i32x4*)&Bs[rb + p1];
      bF[j] = __builtin_shufflevector(lo, hi, 0, 1, 2, 3, 4, 5, 6, 7);
    }
    #pragma unroll
    for (int i = 0; i < 4; ++i)
      #pragma unroll
      for (int j = 0; j < 4; ++j)
        acc[i][j] = __builtin_amdgcn_mfma_scale_f32_16x16x128_f8f6f4(
            aF[i], bF[j], acc[i][j], 0, 0, 0, 0x7F, 0, 0x7F);
  }

  #pragma unroll
  for (int i = 0; i < 4; ++i) {
    #pragma unroll
    for (int j = 0; j < 4; ++j) {
      const int col = n0 + wc + j * 16 + tr;
      const float bv = bias[col];
      #pragma unroll
      for (int r = 0; r < 4; ++r) {
        const int rowg = m0 + wr + i * 16 + tq * 4 + r;
        const size_t idx = (size_t)rowg * N + col;
        const float v = acc[i][j][r] * descale + bv;
        if (MODE == 2) Cb[idx] = (bf16_t)((float)X[idx] * sigmoidf_(v));
        else           Cb[idx] = (bf16_t)v;
      }
    }
  }
}

// ============ bf16 GEMM_BT (out-projection): Cf = acc + bias + R ============
#define BK 32
__global__ __launch_bounds__(256)
void gemm_bt_res(const bf16_t* __restrict__ A, const bf16_t* __restrict__ Bw,
                 const float* __restrict__ bias, const float* __restrict__ R,
                 float* __restrict__ Cf, int M, int N, int K) {
  __shared__ __align__(16) bf16_t As[BM * BK];
  __shared__ __align__(16) bf16_t Bs[BN * BK];

  const int tid  = threadIdx.x;
  const int lane = tid & 63;
  const int wv   = tid >> 6;
  const int m0   = blockIdx.y * BM;
  const int n0   = blockIdx.x * BN;

  const int wr = (wv >> 1) * 64;
  const int wc = (wv & 1) * 64;
  const int tq = lane >> 4;
  const int tr = lane & 15;

  f32x4 acc[4][4] = {};

  const int row0 = tid >> 2;
  const int kp0  = (((tid & 3) ^ ((row0 >> 1) & 3)) * 8);
  const int row1 = row0 + 64;
  const size_t aBase = (size_t)m0 * K;
  const size_t bBase = (size_t)n0 * K;
  char* AsB = (char*)As;
  char* BsB = (char*)Bs;
  const int ldsOff0 = wv * 1024;
  const int ldsOff1 = 4096 + wv * 1024;
  const int sk = (tq ^ ((tr >> 1) & 3)) * 8;

  for (int k0 = 0; k0 < K; k0 += BK) {
    __syncthreads();
    gload_lds16(A  + aBase + (size_t)row0 * K + k0 + kp0, AsB + ldsOff0);
    gload_lds16(A  + aBase + (size_t)row1 * K + k0 + kp0, AsB + ldsOff1);
    gload_lds16(Bw + bBase + (size_t)row0 * K + k0 + kp0, BsB + ldsOff0);
    gload_lds16(Bw + bBase + (size_t)row1 * K + k0 + kp0, BsB + ldsOff1);
    __syncthreads();

    bf16x8 af[4], bfr[4];
    #pragma unroll
    for (int i = 0; i < 4; ++i)
      af[i] = *(const bf16x8*)&As[(wr + i * 16 + tr) * BK + sk];
    #pragma unroll
    for (int j = 0; j < 4; ++j)
      bfr[j] = *(const bf16x8*)&Bs[(wc + j * 16 + tr) * BK + sk];
    #pragma unroll
    for (int i = 0; i < 4; ++i)
      #pragma unroll
      for (int j = 0; j < 4; ++j)
        acc[i][j] = __builtin_amdgcn_mfma_f32_16x16x32_bf16(af[i], bfr[j], acc[i][j], 0, 0, 0);
  }

  #pragma unroll
  for (int i = 0; i < 4; ++i) {
    #pragma unroll
    for (int j = 0; j < 4; ++j) {
      const int col = n0 + wc + j * 16 + tr;
      const float bv = bias[col];
      #pragma unroll
      for (int r = 0; r < 4; ++r) {
        const int rowg = m0 + wr + i * 16 + tq * 4 + r;
        const size_t idx = (size_t)rowg * N + col;
        Cf[idx] = acc[i][j][r] + bv + R[idx];
      }
    }
  }
}

// ---------------- causal depthwise conv (K=4) + silu -> fp8 (scaled) ----------------
__global__ __launch_bounds__(256)
void conv_silu(const bf16_t* __restrict__ xpg, const float* __restrict__ cw,
               const float* __restrict__ cb, u8* __restrict__ xc) {
  const int e  = blockIdx.y * 256 + threadIdx.x;
  const int b  = blockIdx.x >> 9;
  const int s0 = (blockIdx.x & 511) * 4;
  const float w0 = cw[e * 4 + 0], w1 = cw[e * 4 + 1], w2 = cw[e * 4 + 2], w3 = cw[e * 4 + 3];
  const float bias = cb[e];
  float xv[7];
  #pragma unroll
  for (int j = 0; j < 7; ++j) {
    const int s = s0 - 3 + j;
    xv[j] = (s >= 0) ? (float)xpg[(size_t)(b * Sdim + s) * (2 * Edim) + e] : 0.f;
  }
  #pragma unroll
  for (int t = 0; t < 4; ++t) {
    float a = fmaf(w0, xv[t], fmaf(w1, xv[t + 1], fmaf(w2, xv[t + 2], fmaf(w3, xv[t + 3], bias))));
    float y = a * sigmoidf_(a) * XCSCALE;
    int p = __builtin_amdgcn_cvt_pk_fp8_f32(y, y, 0, 0);
    xc[(size_t)(b * Sdim + s0 + t) * Edim + e] = (u8)(p & 0xff);
  }
}

// ---------------- chunked parallel scan ----------------
__global__ __launch_bounds__(256)
void scan_part1(const bf16_t* __restrict__ u, const float* __restrict__ aexp,
                float* __restrict__ zloc) {
  const int c    = blockIdx.x;
  const int b    = blockIdx.y >> 3;
  const int eblk = blockIdx.y & 7;
  const int e    = eblk * 256 + threadIdx.x;
  const float a  = aexp[e];
  const bf16_t* up = u + ((size_t)(b * Sdim + c * CL)) * Edim + e;
  float z = 0.f;
  #pragma unroll
  for (int t = 0; t < CL; ++t) z = fmaf(a, z, (float)up[(size_t)t * Edim]);
  zloc[((size_t)b * CH + c) * Edim + e] = z;
}

__global__ __launch_bounds__(256)
void scan_part2(const float* __restrict__ aexp, float* __restrict__ zloc) {
  const int idx = blockIdx.x * 256 + threadIdx.x;
  const int b = idx >> 11, e = idx & (Edim - 1);
  float a  = aexp[e];
  float aL = a * a;
  aL = aL * aL; aL = aL * aL; aL = aL * aL; aL = aL * aL;  // a^32
  float* zp = zloc + (size_t)b * CH * Edim + e;
  float pref = 0.f;
  #pragma unroll 4
  for (int c = 0; c < CH; ++c) {
    const float loc = zp[(size_t)c * Edim];
    zp[(size_t)c * Edim] = pref;
    pref = fmaf(aL, pref, loc);
  }
}

__global__ __launch_bounds__(256)
void scan_part3(const bf16_t* __restrict__ u, const bf16_t* __restrict__ xpg,
                const float* __restrict__ aexp, const float* __restrict__ Ce,
                const float* __restrict__ zloc, bf16_t* __restrict__ xg) {
  const int c    = blockIdx.x;
  const int b    = blockIdx.y >> 3;
  const int eblk = blockIdx.y & 7;
  const int e    = eblk * 256 + threadIdx.x;
  const float a = aexp[e], C = Ce[e];
  float z = zloc[((size_t)b * CH + c) * Edim + e];
  const bf16_t* up = u   + ((size_t)(b * Sdim + c * CL)) * Edim + e;
  const bf16_t* gp = xpg + ((size_t)(b * Sdim + c * CL)) * (2 * Edim) + Edim + e;
  bf16_t*       op = xg  + ((size_t)(b * Sdim + c * CL)) * Edim + e;
  #pragma unroll 8
  for (int t = 0; t < CL; ++t) {
    z = fmaf(a, z, (float)up[(size_t)t * Edim]);
    const float gv = (float)gp[(size_t)t * (2 * Edim)];
    op[(size_t)t * Edim] = (bf16_t)(C * z * sigmoidf_(gv));
  }
}

extern "C" void kernel_launch(void* const* d_in, const int* in_sizes, int n_in,
                              void* d_out, int out_size, void* d_ws, size_t ws_size,
                              hipStream_t stream) {
  const float* x         = (const float*)d_in[0];
  const float* ln_g      = (const float*)d_in[1];
  const float* ln_b      = (const float*)d_in[2];
  const float* W_in      = (const float*)d_in[3];
  const float* b_in      = (const float*)d_in[4];
  const float* conv_w    = (const float*)d_in[5];
  const float* conv_b    = (const float*)d_in[6];
  const float* Am        = (const float*)d_in[7];
  const float* Bm        = (const float*)d_in[8];
  const float* W_c       = (const float*)d_in[9];
  const float* b_c       = (const float*)d_in[10];
  const float* W_d       = (const float*)d_in[11];
  const float* b_d       = (const float*)d_in[12];
  const float* log_delta = (const float*)d_in[13];
  const float* W_out     = (const float*)d_in[14];
  const float* b_out     = (const float*)d_in[15];
  float* out = (float*)d_out;

  const size_t MiB = 1024 * 1024;
  char* w = (char*)d_ws;
  u8*     wWin8 = (u8*)    (w + 0);            //  4 MiB (4096x1024)
  u8*     wWc8  = (u8*)    (w + 4 * MiB);      //  4 MiB
  u8*     wWd8  = (u8*)    (w + 8 * MiB);      //  4 MiB
  bf16_t* wWout = (bf16_t*)(w + 12 * MiB);     //  4 MiB (1024x2048 bf16)
  float*  aexp  = (float*) (w + 16 * MiB);
  float*  Ce    = (float*) (w + 16 * MiB + 16384);
  float*  zloc  = (float*) (w + 16 * MiB + 65536);  // 2 MiB
  u8*     xln8  = (u8*)    (w + 19 * MiB);     //  8 MiB (8192x1024)
  bf16_t* xpg   = (bf16_t*)(w + 27 * MiB);     // 64 MiB (8192x4096 bf16)
  u8*     xc8   = (u8*)    (w + 91 * MiB);     // 16 MiB (8192x2048)
  bf16_t* cbuf  = (bf16_t*)(w + 107 * MiB);    // 32 MiB (c)
  bf16_t* ubuf  = (bf16_t*)(w + 139 * MiB);    // 32 MiB (u)
  bf16_t* gbuf  = (bf16_t*)(w + 171 * MiB);    // 32 MiB (xg) -> 203 MiB

  const int M = Bdim * Sdim;  // 8192
  const float dsIn = 1.f / WSCALE;
  const float dsCD = 1.f / (WSCALE * XCSCALE);

  cvt_fp8_3<<<3 * 4096, 256, 0, stream>>>(W_in, W_c, W_d, wWin8, wWc8, wWd8);
  cvt_bf16<<<(Ddim * Edim) / 256, 256, 0, stream>>>(W_out, wWout, Ddim * Edim);
  prep_scalars<<<Edim / 256, 256, 0, stream>>>(log_delta, Am, Bm, aexp, Ce);

  ln_kernel<<<M, 256, 0, stream>>>(x, ln_g, ln_b, xln8);

  // x_proj = x_ln @ W_in^T + b_in  (MX fp8 -> bf16 xpg)
  gemm_mx<0><<<dim3((2 * Edim) / BN, M / BM), 256, 0, stream>>>(
      xln8, wWin8, b_in, nullptr, xpg, dsIn, M, 2 * Edim, Ddim);

  conv_silu<<<dim3(Bdim * (Sdim / 4), Edim / 256), 256, 0, stream>>>(xpg, conv_w, conv_b, xc8);

  // c = xc @ Wc^T + bc
  gemm_mx<0><<<dim3(Edim / BN, M / BM), 256, 0, stream>>>(
      xc8, wWc8, b_c, nullptr, cbuf, dsCD, M, Edim, Edim);
  // u = c * sigmoid(xc @ Wd^T + bd)
  gemm_mx<2><<<dim3(Edim / BN, M / BM), 256, 0, stream>>>(
      xc8, wWd8, b_d, cbuf, ubuf, dsCD, M, Edim, Edim);

  scan_part1<<<dim3(CH, Bdim * (Edim / 256)), 256, 0, stream>>>(ubuf, aexp, zloc);
  scan_part2<<<(Bdim * Edim) / 256, 256, 0, stream>>>(aexp, zloc);
  scan_part3<<<dim3(CH, Bdim * (Edim / 256)), 256, 0, stream>>>(ubuf, xpg, aexp, Ce, zloc, gbuf);

  // out = xg @ W_out^T + b_out + x  (bf16 GEMM, fp32 out)
  gemm_bt_res<<<dim3(Ddim / BN, M / BM), 256, 0, stream>>>(
      gbuf, wWout, b_out, x, out, M, Ddim, Edim);

  (void)in_sizes; (void)n_in; (void)out_size; (void)ws_size;
}

// Round 6
// 374.219 us; speedup vs baseline: 1.8173x; 1.0936x over previous
//
#include <hip/hip_runtime.h>
#include <hip/hip_bf16.h>

typedef __bf16 bf16_t;
typedef unsigned char u8;
typedef __bf16 bf16x8 __attribute__((ext_vector_type(8)));
typedef __bf16 bf16x4 __attribute__((ext_vector_type(4)));
typedef float  f32x4  __attribute__((ext_vector_type(4)));
typedef int    i32x4  __attribute__((ext_vector_type(4)));
typedef int    i32x8  __attribute__((ext_vector_type(8)));
typedef __attribute__((address_space(3))) unsigned as3u32;
typedef __attribute__((address_space(1))) unsigned as1u32;

#define Bdim 4
#define Sdim 2048
#define Ddim 1024
#define Edim 2048
#define CH 64
#define CL 32

#define WSCALE 32.0f   // weight fp8 pre-scale
#define XCSCALE 16.0f  // conv activation fp8 pre-scale
#define GSCALE 256.0f  // xg fp8 pre-scale

__device__ __forceinline__ void gload_lds16(const void* g, void* l) {
  __builtin_amdgcn_global_load_lds((const as1u32*)g, (as3u32*)l, 16, 0, 0);
}
__device__ __forceinline__ float sigmoidf_(float x) {
  return 1.f / (1.f + __expf(-x));
}
__device__ __forceinline__ int pk_fp8x4(float a, float b, float c, float d) {
  int p = __builtin_amdgcn_cvt_pk_fp8_f32(a, b, 0, 0);
  p = __builtin_amdgcn_cvt_pk_fp8_f32(c, d, p, 1);
  return p;
}

// ---------------- 3 big weight arrays fp32 -> fp8 (each 4194304 elts) ----
__global__ __launch_bounds__(256)
void cvt_fp8_3(const float* __restrict__ s0, const float* __restrict__ s1,
               const float* __restrict__ s2, u8* __restrict__ d0,
               u8* __restrict__ d1, u8* __restrict__ d2) {
  const int seg = blockIdx.x >> 12;
  const int i   = ((blockIdx.x & 4095) * 256 + threadIdx.x) * 4;
  const float* s = (seg == 0) ? s0 : (seg == 1) ? s1 : s2;
  u8*          d = (seg == 0) ? d0 : (seg == 1) ? d1 : d2;
  *(int*)(d + i) = pk_fp8x4(s[i] * WSCALE, s[i + 1] * WSCALE,
                            s[i + 2] * WSCALE, s[i + 3] * WSCALE);
}

// ---------------- generic fp32 -> fp8 (W_out) ----------------
__global__ __launch_bounds__(256)
void cvt_fp8(const float* __restrict__ s, u8* __restrict__ d, int n, float scale) {
  int i = (blockIdx.x * 256 + threadIdx.x) * 4;
  if (i < n)
    *(int*)(d + i) = pk_fp8x4(s[i] * scale, s[i + 1] * scale,
                              s[i + 2] * scale, s[i + 3] * scale);
}

// ---------------- scan scalars ----------------
__global__ __launch_bounds__(256)
void prep_scalars(const float* __restrict__ ld, const float* __restrict__ Am,
                  const float* __restrict__ Bm, float* __restrict__ aexp,
                  float* __restrict__ Ce) {
  int e = blockIdx.x * 256 + threadIdx.x;
  if (e >= Edim) return;
  float d = ld[e];
  float sp = (d > 20.f) ? d : log1pf(expf(d));
  aexp[e] = expf(-sp);
  float s = 0.f;
  #pragma unroll
  for (int n = 0; n < 16; ++n) s += Am[e * 16 + n] * Bm[e * 16 + n];
  Ce[e] = s;
}

// ---------------- layernorm -> fp8 ----------------
__global__ __launch_bounds__(256)
void ln_kernel(const float* __restrict__ x, const float* __restrict__ g,
               const float* __restrict__ b, u8* __restrict__ out) {
  const int row = blockIdx.x;
  const int tid = threadIdx.x;
  const float4 v = ((const float4*)(x + (size_t)row * Ddim))[tid];
  float s  = v.x + v.y + v.z + v.w;
  float ss = v.x * v.x + v.y * v.y + v.z * v.z + v.w * v.w;
  #pragma unroll
  for (int o = 32; o > 0; o >>= 1) { s += __shfl_down(s, o); ss += __shfl_down(ss, o); }
  __shared__ float sh[8];
  const int wv = tid >> 6, lane = tid & 63;
  if (lane == 0) { sh[wv] = s; sh[4 + wv] = ss; }
  __syncthreads();
  s  = sh[0] + sh[1] + sh[2] + sh[3];
  ss = sh[4] + sh[5] + sh[6] + sh[7];
  const float mean = s * (1.f / Ddim);
  const float var  = ss * (1.f / Ddim) - mean * mean;
  const float rstd = rsqrtf(var + 1e-5f);
  const float4 gv = ((const float4*)g)[tid];
  const float4 bv = ((const float4*)b)[tid];
  *(int*)(out + (size_t)row * Ddim + tid * 4) =
      pk_fp8x4((v.x - mean) * rstd * gv.x + bv.x,
               (v.y - mean) * rstd * gv.y + bv.y,
               (v.z - mean) * rstd * gv.z + bv.z,
               (v.w - mean) * rstd * gv.w + bv.w);
}

// ============ MX fp8 GEMM_BT: 128x128 tile, BK=128, mfma_scale 16x16x128 =========
// acc = (A8 @ B8^T); v = acc*descale + bias.
// MODE 0: Cb = bf16(v). MODE 1: Cf = v + R (fp32). MODE 2: Cb = bf16(X*sigmoid(v)).
#define BM 128
#define BN 128

template<int MODE>
__global__ __launch_bounds__(256)
void gemm_mx(const u8* __restrict__ A, const u8* __restrict__ Bw,
             const float* __restrict__ bias, const bf16_t* __restrict__ X,
             const float* __restrict__ R, bf16_t* __restrict__ Cb,
             float* __restrict__ Cf, float descale, int M, int N, int K) {
  __shared__ __align__(16) u8 As[BM * 128];
  __shared__ __align__(16) u8 Bs[BN * 128];

  const int tid  = threadIdx.x;
  const int lane = tid & 63;
  const int wv   = tid >> 6;
  const int m0   = blockIdx.y * BM;
  const int n0   = blockIdx.x * BN;

  const int wr = (wv >> 1) * 64;
  const int wc = (wv & 1) * 64;
  const int tq = lane >> 4;
  const int tr = lane & 15;

  f32x4 acc[4][4] = {};

  size_t srcOff[4];
  int    ldsOff[4];
  #pragma unroll
  for (int g = 0; g < 4; ++g) {
    const int p   = g * 256 + tid;
    const int row = p >> 3;
    const int c   = (p & 7) ^ (row & 7);
    srcOff[g] = (size_t)row * K + c * 16;
    ldsOff[g] = g * 4096 + wv * 1024;
  }
  const size_t aBase = (size_t)m0 * K;
  const size_t bBase = (size_t)n0 * K;
  char* AsB = (char*)As;
  char* BsB = (char*)Bs;

  const int s7 = tr & 7;
  const int p0 = (((tq << 1)) ^ s7) * 16;
  const int p1 = (((tq << 1) | 1) ^ s7) * 16;

  for (int k0 = 0; k0 < K; k0 += 128) {
    __syncthreads();
    #pragma unroll
    for (int g = 0; g < 4; ++g)
      gload_lds16(A + aBase + srcOff[g] + k0, AsB + ldsOff[g]);
    #pragma unroll
    for (int g = 0; g < 4; ++g)
      gload_lds16(Bw + bBase + srcOff[g] + k0, BsB + ldsOff[g]);
    __syncthreads();

    i32x8 aF[4], bF[4];
    #pragma unroll
    for (int i = 0; i < 4; ++i) {
      const int rb = (wr + i * 16 + tr) * 128;
      const i32x4 lo = *(const i32x4*)&As[rb + p0];
      const i32x4 hi = *(const i32x4*)&As[rb + p1];
      aF[i] = __builtin_shufflevector(lo, hi, 0, 1, 2, 3, 4, 5, 6, 7);
    }
    #pragma unroll
    for (int j = 0; j < 4; ++j) {
      const int rb = (wc + j * 16 + tr) * 128;
      const i32x4 lo = *(const i32x4*)&Bs[rb + p0];
      const i32x4 hi = *(const i32x4*)&Bs[rb + p1];
      bF[j] = __builtin_shufflevector(lo, hi, 0, 1, 2, 3, 4, 5, 6, 7);
    }
    #pragma unroll
    for (int i = 0; i < 4; ++i)
      #pragma unroll
      for (int j = 0; j < 4; ++j)
        acc[i][j] = __builtin_amdgcn_mfma_scale_f32_16x16x128_f8f6f4(
            aF[i], bF[j], acc[i][j], 0, 0, 0, 0x7F, 0, 0x7F);
  }

  #pragma unroll
  for (int i = 0; i < 4; ++i) {
    #pragma unroll
    for (int j = 0; j < 4; ++j) {
      const int col = n0 + wc + j * 16 + tr;
      const float bv = bias[col];
      #pragma unroll
      for (int r = 0; r < 4; ++r) {
        const int rowg = m0 + wr + i * 16 + tq * 4 + r;
        const size_t idx = (size_t)rowg * N + col;
        const float v = acc[i][j][r] * descale + bv;
        if (MODE == 1)      Cf[idx] = v + R[idx];
        else if (MODE == 2) Cb[idx] = (bf16_t)((float)X[idx] * sigmoidf_(v));
        else                Cb[idx] = (bf16_t)v;
      }
    }
  }
}

// ---------------- causal depthwise conv (K=4) + silu -> fp8 (scaled) ----------------
__global__ __launch_bounds__(256)
void conv_silu(const bf16_t* __restrict__ xpg, const float* __restrict__ cw,
               const float* __restrict__ cb, u8* __restrict__ xc) {
  const int e  = blockIdx.y * 256 + threadIdx.x;
  const int b  = blockIdx.x >> 9;
  const int s0 = (blockIdx.x & 511) * 4;
  const float w0 = cw[e * 4 + 0], w1 = cw[e * 4 + 1], w2 = cw[e * 4 + 2], w3 = cw[e * 4 + 3];
  const float bias = cb[e];
  float xv[7];
  #pragma unroll
  for (int j = 0; j < 7; ++j) {
    const int s = s0 - 3 + j;
    xv[j] = (s >= 0) ? (float)xpg[(size_t)(b * Sdim + s) * (2 * Edim) + e] : 0.f;
  }
  #pragma unroll
  for (int t = 0; t < 4; ++t) {
    float a = fmaf(w0, xv[t], fmaf(w1, xv[t + 1], fmaf(w2, xv[t + 2], fmaf(w3, xv[t + 3], bias))));
    float y = a * sigmoidf_(a) * XCSCALE;
    int p = __builtin_amdgcn_cvt_pk_fp8_f32(y, y, 0, 0);
    xc[(size_t)(b * Sdim + s0 + t) * Edim + e] = (u8)(p & 0xff);
  }
}

// ---------------- chunked parallel scan ----------------
__global__ __launch_bounds__(256)
void scan_part1(const bf16_t* __restrict__ u, const float* __restrict__ aexp,
                float* __restrict__ zloc) {
  const int c    = blockIdx.x;
  const int b    = blockIdx.y >> 3;
  const int eblk = blockIdx.y & 7;
  const int e    = eblk * 256 + threadIdx.x;
  const float a  = aexp[e];
  const bf16_t* up = u + ((size_t)(b * Sdim + c * CL)) * Edim + e;
  float z = 0.f;
  #pragma unroll
  for (int t = 0; t < CL; ++t) z = fmaf(a, z, (float)up[(size_t)t * Edim]);
  zloc[((size_t)b * CH + c) * Edim + e] = z;
}

__global__ __launch_bounds__(256)
void scan_part2(const float* __restrict__ aexp, float* __restrict__ zloc) {
  const int idx = blockIdx.x * 256 + threadIdx.x;
  const int b = idx >> 11, e = idx & (Edim - 1);
  float a  = aexp[e];
  float aL = a * a;
  aL = aL * aL; aL = aL * aL; aL = aL * aL; aL = aL * aL;  // a^32
  float* zp = zloc + (size_t)b * CH * Edim + e;
  float pref = 0.f;
  #pragma unroll 4
  for (int c = 0; c < CH; ++c) {
    const float loc = zp[(size_t)c * Edim];
    zp[(size_t)c * Edim] = pref;
    pref = fmaf(aL, pref, loc);
  }
}

// Phase 3: re-scan, gate, write xg as fp8 (x GSCALE)
__global__ __launch_bounds__(256)
void scan_part3(const bf16_t* __restrict__ u, const bf16_t* __restrict__ xpg,
                const float* __restrict__ aexp, const float* __restrict__ Ce,
                const float* __restrict__ zloc, u8* __restrict__ xg8) {
  const int c    = blockIdx.x;
  const int b    = blockIdx.y >> 3;
  const int eblk = blockIdx.y & 7;
  const int e    = eblk * 256 + threadIdx.x;
  const float a = aexp[e], C = Ce[e];
  float z = zloc[((size_t)b * CH + c) * Edim + e];
  const bf16_t* up = u   + ((size_t)(b * Sdim + c * CL)) * Edim + e;
  const bf16_t* gp = xpg + ((size_t)(b * Sdim + c * CL)) * (2 * Edim) + Edim + e;
  u8*           op = xg8 + ((size_t)(b * Sdim + c * CL)) * Edim + e;
  #pragma unroll 8
  for (int t = 0; t < CL; ++t) {
    z = fmaf(a, z, (float)up[(size_t)t * Edim]);
    const float gv = (float)gp[(size_t)t * (2 * Edim)];
    const float y  = C * z * sigmoidf_(gv) * GSCALE;
    int p = __builtin_amdgcn_cvt_pk_fp8_f32(y, y, 0, 0);
    op[(size_t)t * Edim] = (u8)(p & 0xff);
  }
}

extern "C" void kernel_launch(void* const* d_in, const int* in_sizes, int n_in,
                              void* d_out, int out_size, void* d_ws, size_t ws_size,
                              hipStream_t stream) {
  const float* x         = (const float*)d_in[0];
  const float* ln_g      = (const float*)d_in[1];
  const float* ln_b      = (const float*)d_in[2];
  const float* W_in      = (const float*)d_in[3];
  const float* b_in      = (const float*)d_in[4];
  const float* conv_w    = (const float*)d_in[5];
  const float* conv_b    = (const float*)d_in[6];
  const float* Am        = (const float*)d_in[7];
  const float* Bm        = (const float*)d_in[8];
  const float* W_c       = (const float*)d_in[9];
  const float* b_c       = (const float*)d_in[10];
  const float* W_d       = (const float*)d_in[11];
  const float* b_d       = (const float*)d_in[12];
  const float* log_delta = (const float*)d_in[13];
  const float* W_out     = (const float*)d_in[14];
  const float* b_out     = (const float*)d_in[15];
  float* out = (float*)d_out;

  const size_t MiB = 1024 * 1024;
  char* w = (char*)d_ws;
  u8*     wWin8  = (u8*)    (w + 0);            //  4 MiB (4096x1024)
  u8*     wWc8   = (u8*)    (w + 4 * MiB);      //  4 MiB
  u8*     wWd8   = (u8*)    (w + 8 * MiB);      //  4 MiB
  u8*     wWout8 = (u8*)    (w + 12 * MiB);     //  2 MiB (1024x2048)
  float*  aexp   = (float*) (w + 15 * MiB);
  float*  Ce     = (float*) (w + 15 * MiB + 16384);
  float*  zloc   = (float*) (w + 15 * MiB + 65536);  // 2 MiB
  u8*     xln8   = (u8*)    (w + 18 * MiB);     //  8 MiB (8192x1024)
  bf16_t* xpg    = (bf16_t*)(w + 26 * MiB);     // 64 MiB (8192x4096 bf16)
  u8*     xc8    = (u8*)    (w + 90 * MiB);     // 16 MiB (8192x2048)
  bf16_t* cbuf   = (bf16_t*)(w + 106 * MiB);    // 32 MiB (c)
  bf16_t* ubuf   = (bf16_t*)(w + 138 * MiB);    // 32 MiB (u)
  u8*     xg8    = (u8*)    (w + 170 * MiB);    // 16 MiB (xg fp8) -> 186 MiB

  const int M = Bdim * Sdim;  // 8192
  const float dsIn  = 1.f / WSCALE;
  const float dsCD  = 1.f / (WSCALE * XCSCALE);
  const float dsOut = 1.f / (WSCALE * GSCALE);

  cvt_fp8_3<<<3 * 4096, 256, 0, stream>>>(W_in, W_c, W_d, wWin8, wWc8, wWd8);
  cvt_fp8<<<(Ddim * Edim) / 1024, 256, 0, stream>>>(W_out, wWout8, Ddim * Edim, WSCALE);
  prep_scalars<<<Edim / 256, 256, 0, stream>>>(log_delta, Am, Bm, aexp, Ce);

  ln_kernel<<<M, 256, 0, stream>>>(x, ln_g, ln_b, xln8);

  // x_proj = x_ln @ W_in^T + b_in  (MX fp8 -> bf16 xpg)
  gemm_mx<0><<<dim3((2 * Edim) / BN, M / BM), 256, 0, stream>>>(
      xln8, wWin8, b_in, nullptr, nullptr, xpg, nullptr, dsIn, M, 2 * Edim, Ddim);

  conv_silu<<<dim3(Bdim * (Sdim / 4), Edim / 256), 256, 0, stream>>>(xpg, conv_w, conv_b, xc8);

  // c = xc @ Wc^T + bc
  gemm_mx<0><<<dim3(Edim / BN, M / BM), 256, 0, stream>>>(
      xc8, wWc8, b_c, nullptr, nullptr, cbuf, nullptr, dsCD, M, Edim, Edim);
  // u = c * sigmoid(xc @ Wd^T + bd)
  gemm_mx<2><<<dim3(Edim / BN, M / BM), 256, 0, stream>>>(
      xc8, wWd8, b_d, cbuf, nullptr, ubuf, nullptr, dsCD, M, Edim, Edim);

  scan_part1<<<dim3(CH, Bdim * (Edim / 256)), 256, 0, stream>>>(ubuf, aexp, zloc);
  scan_part2<<<(Bdim * Edim) / 256, 256, 0, stream>>>(aexp, zloc);
  scan_part3<<<dim3(CH, Bdim * (Edim / 256)), 256, 0, stream>>>(ubuf, xpg, aexp, Ce, zloc, xg8);

  // out = xg @ W_out^T + b_out + x  (MX fp8, fp32 out with residual)
  gemm_mx<1><<<dim3(Ddim / BN, M / BM), 256, 0, stream>>>(
      xg8, wWout8, b_out, nullptr, x, nullptr, out, dsOut, M, Ddim, Edim);

  (void)in_sizes; (void)n_in; (void)out_size; (void)ws_size;
}

// Round 8
// 372.999 us; speedup vs baseline: 1.8232x; 1.0033x over previous
//
#include <hip/hip_runtime.h>
#include <hip/hip_bf16.h>

typedef __bf16 bf16_t;
typedef unsigned char u8;
typedef float  f32x4  __attribute__((ext_vector_type(4)));
typedef int    i32x4  __attribute__((ext_vector_type(4)));
typedef int    i32x8  __attribute__((ext_vector_type(8)));
typedef __attribute__((address_space(3))) unsigned as3u32;
typedef __attribute__((address_space(1))) unsigned as1u32;

#define Bdim 4
#define Sdim 2048
#define Ddim 1024
#define Edim 2048
#define CH 64
#define CL 32

#define WSCALE 32.0f   // weight fp8 pre-scale
#define XPSCALE 32.0f  // xp / gate fp8 pre-scale
#define XCSCALE 16.0f  // conv output fp8 pre-scale
#define CSCALE 16.0f   // c and u fp8 pre-scale
#define GSCALE 256.0f  // xg fp8 pre-scale

__device__ __forceinline__ void gload_lds16(const void* g, void* l) {
  __builtin_amdgcn_global_load_lds((const as1u32*)g, (as3u32*)l, 16, 0, 0);
}
__device__ __forceinline__ float sigmoidf_(float x) {
  return 1.f / (1.f + __expf(-x));
}
__device__ __forceinline__ int pk_fp8x4(float a, float b, float c, float d) {
  int p = __builtin_amdgcn_cvt_pk_fp8_f32(a, b, 0, 0);
  p = __builtin_amdgcn_cvt_pk_fp8_f32(c, d, p, 1);
  return p;
}
template<int K>
__device__ __forceinline__ float dq8(int v) {
  return __builtin_amdgcn_cvt_f32_fp8(v, K);   // K must be a front-end constant
}
__device__ __forceinline__ u8 q8(float v) {
  return (u8)(__builtin_amdgcn_cvt_pk_fp8_f32(v, v, 0, 0) & 0xff);
}

// ---------------- 3 big weight arrays fp32 -> fp8 ----------------
__global__ __launch_bounds__(256)
void cvt_fp8_3(const float* __restrict__ s0, const float* __restrict__ s1,
               const float* __restrict__ s2, u8* __restrict__ d0,
               u8* __restrict__ d1, u8* __restrict__ d2) {
  const int seg = blockIdx.x >> 12;
  const int i   = ((blockIdx.x & 4095) * 256 + threadIdx.x) * 4;
  const float* s = (seg == 0) ? s0 : (seg == 1) ? s1 : s2;
  u8*          d = (seg == 0) ? d0 : (seg == 1) ? d1 : d2;
  *(int*)(d + i) = pk_fp8x4(s[i] * WSCALE, s[i + 1] * WSCALE,
                            s[i + 2] * WSCALE, s[i + 3] * WSCALE);
}

// ---------------- generic fp32 -> fp8 (W_out) ----------------
__global__ __launch_bounds__(256)
void cvt_fp8(const float* __restrict__ s, u8* __restrict__ d, int n, float scale) {
  int i = (blockIdx.x * 256 + threadIdx.x) * 4;
  if (i < n)
    *(int*)(d + i) = pk_fp8x4(s[i] * scale, s[i + 1] * scale,
                              s[i + 2] * scale, s[i + 3] * scale);
}

// ---------------- scan scalars ----------------
__global__ __launch_bounds__(256)
void prep_scalars(const float* __restrict__ ld, const float* __restrict__ Am,
                  const float* __restrict__ Bm, float* __restrict__ aexp,
                  float* __restrict__ Ce) {
  int e = blockIdx.x * 256 + threadIdx.x;
  if (e >= Edim) return;
  float d = ld[e];
  float sp = (d > 20.f) ? d : log1pf(expf(d));
  aexp[e] = expf(-sp);
  float s = 0.f;
  #pragma unroll
  for (int n = 0; n < 16; ++n) s += Am[e * 16 + n] * Bm[e * 16 + n];
  Ce[e] = s;
}

// ---------------- layernorm -> fp8 (scale 1) ----------------
__global__ __launch_bounds__(256)
void ln_kernel(const float* __restrict__ x, const float* __restrict__ g,
               const float* __restrict__ b, u8* __restrict__ out) {
  const int row = blockIdx.x;
  const int tid = threadIdx.x;
  const float4 v = ((const float4*)(x + (size_t)row * Ddim))[tid];
  float s  = v.x + v.y + v.z + v.w;
  float ss = v.x * v.x + v.y * v.y + v.z * v.z + v.w * v.w;
  #pragma unroll
  for (int o = 32; o > 0; o >>= 1) { s += __shfl_down(s, o); ss += __shfl_down(ss, o); }
  __shared__ float sh[8];
  const int wv = tid >> 6, lane = tid & 63;
  if (lane == 0) { sh[wv] = s; sh[4 + wv] = ss; }
  __syncthreads();
  s  = sh[0] + sh[1] + sh[2] + sh[3];
  ss = sh[4] + sh[5] + sh[6] + sh[7];
  const float mean = s * (1.f / Ddim);
  const float var  = ss * (1.f / Ddim) - mean * mean;
  const float rstd = rsqrtf(var + 1e-5f);
  const float4 gv = ((const float4*)g)[tid];
  const float4 bv = ((const float4*)b)[tid];
  *(int*)(out + (size_t)row * Ddim + tid * 4) =
      pk_fp8x4((v.x - mean) * rstd * gv.x + bv.x,
               (v.y - mean) * rstd * gv.y + bv.y,
               (v.z - mean) * rstd * gv.z + bv.z,
               (v.w - mean) * rstd * gv.w + bv.w);
}

// ============ MX fp8 GEMM_BT: 128x128 tile, BK=128, mfma_scale 16x16x128 =========
// acc = A8 @ B8^T; v = acc*descale + bias.
// MODE 1: Cf[idx] = v + R[idx]                (fp32 out, residual)
// MODE 2: C8[idx] = fp8( dq(X8[idx]) * sigmoid(v) )   (u = c*sigmoid(d), scaled)
// MODE 3: C8[idx] = fp8( v * oscale )
#define BM 128
#define BN 128

template<int MODE>
__global__ __launch_bounds__(256)
void gemm_mx(const u8* __restrict__ A, const u8* __restrict__ Bw,
             const float* __restrict__ bias, const u8* __restrict__ X,
             const float* __restrict__ R, u8* __restrict__ C8,
             float* __restrict__ Cf, float descale, float oscale,
             int M, int N, int K) {
  __shared__ __align__(16) u8 As[BM * 128];
  __shared__ __align__(16) u8 Bs[BN * 128];

  const int tid  = threadIdx.x;
  const int lane = tid & 63;
  const int wv   = tid >> 6;
  const int m0   = blockIdx.y * BM;
  const int n0   = blockIdx.x * BN;

  const int wr = (wv >> 1) * 64;
  const int wc = (wv & 1) * 64;
  const int tq = lane >> 4;
  const int tr = lane & 15;

  f32x4 acc[4][4] = {};

  size_t srcOff[4];
  int    ldsOff[4];
  #pragma unroll
  for (int g = 0; g < 4; ++g) {
    const int p   = g * 256 + tid;
    const int row = p >> 3;
    const int c   = (p & 7) ^ (row & 7);
    srcOff[g] = (size_t)row * K + c * 16;
    ldsOff[g] = g * 4096 + wv * 1024;
  }
  const size_t aBase = (size_t)m0 * K;
  const size_t bBase = (size_t)n0 * K;
  char* AsB = (char*)As;
  char* BsB = (char*)Bs;

  const int s7 = tr & 7;
  const int p0 = (((tq << 1)) ^ s7) * 16;
  const int p1 = (((tq << 1) | 1) ^ s7) * 16;

  for (int k0 = 0; k0 < K; k0 += 128) {
    __syncthreads();
    #pragma unroll
    for (int g = 0; g < 4; ++g)
      gload_lds16(A + aBase + srcOff[g] + k0, AsB + ldsOff[g]);
    #pragma unroll
    for (int g = 0; g < 4; ++g)
      gload_lds16(Bw + bBase + srcOff[g] + k0, BsB + ldsOff[g]);
    __syncthreads();

    i32x8 aF[4], bF[4];
    #pragma unroll
    for (int i = 0; i < 4; ++i) {
      const int rb = (wr + i * 16 + tr) * 128;
      const i32x4 lo = *(const i32x4*)&As[rb + p0];
      const i32x4 hi = *(const i32x4*)&As[rb + p1];
      aF[i] = __builtin_shufflevector(lo, hi, 0, 1, 2, 3, 4, 5, 6, 7);
    }
    #pragma unroll
    for (int j = 0; j < 4; ++j) {
      const int rb = (wc + j * 16 + tr) * 128;
      const i32x4 lo = *(const i32x4*)&Bs[rb + p0];
      const i32x4 hi = *(const i32x4*)&Bs[rb + p1];
      bF[j] = __builtin_shufflevector(lo, hi, 0, 1, 2, 3, 4, 5, 6, 7);
    }
    #pragma unroll
    for (int i = 0; i < 4; ++i)
      #pragma unroll
      for (int j = 0; j < 4; ++j)
        acc[i][j] = __builtin_amdgcn_mfma_scale_f32_16x16x128_f8f6f4(
            aF[i], bF[j], acc[i][j], 0, 0, 0, 0x7F, 0, 0x7F);
  }

  #pragma unroll
  for (int i = 0; i < 4; ++i) {
    #pragma unroll
    for (int j = 0; j < 4; ++j) {
      const int col = n0 + wc + j * 16 + tr;
      const float bv = bias[col];
      #pragma unroll
      for (int r = 0; r < 4; ++r) {
        const int rowg = m0 + wr + i * 16 + tq * 4 + r;
        const size_t idx = (size_t)rowg * N + col;
        const float v = acc[i][j][r] * descale + bv;
        if (MODE == 1) {
          Cf[idx] = v + R[idx];
        } else if (MODE == 2) {
          const float xv = dq8<0>((int)X[idx]);   // raw = c*CSCALE
          C8[idx] = q8(xv * sigmoidf_(v));        // = u*CSCALE
        } else {
          C8[idx] = q8(v * oscale);
        }
      }
    }
  }
}

// ---------------- causal depthwise conv (K=4) + silu, fp8 in/out, 4 e/thread ----
__global__ __launch_bounds__(256)
void conv_silu(const u8* __restrict__ xpg8, const float* __restrict__ cw,
               const float* __restrict__ cb, u8* __restrict__ xc8) {
  const int e0 = (blockIdx.y * 256 + threadIdx.x) * 4;   // gridDim.y = Edim/1024
  const int b  = blockIdx.x >> 9;
  const int s0 = (blockIdx.x & 511) * 4;
  float w[4][4], bias[4];
  #pragma unroll
  for (int k = 0; k < 4; ++k) {
    const float4 wv = *(const float4*)(cw + (e0 + k) * 4);
    w[k][0] = wv.x; w[k][1] = wv.y; w[k][2] = wv.z; w[k][3] = wv.w;
    bias[k] = cb[e0 + k];
  }
  float f[7][4];
  #pragma unroll
  for (int j = 0; j < 7; ++j) {
    const int s = s0 - 3 + j;
    const int xv = (s >= 0) ? *(const int*)(xpg8 + (size_t)(b * Sdim + s) * (2 * Edim) + e0) : 0;
    f[j][0] = dq8<0>(xv); f[j][1] = dq8<1>(xv);
    f[j][2] = dq8<2>(xv); f[j][3] = dq8<3>(xv);
  }
  #pragma unroll
  for (int t = 0; t < 4; ++t) {
    float y[4];
    #pragma unroll
    for (int k = 0; k < 4; ++k) {
      float a = fmaf(w[k][0], f[t][k],
               fmaf(w[k][1], f[t + 1][k],
               fmaf(w[k][2], f[t + 2][k],
                    w[k][3] * f[t + 3][k])));
      a = a * (1.f / XPSCALE) + bias[k];
      y[k] = a * sigmoidf_(a) * XCSCALE;
    }
    *(int*)(xc8 + (size_t)(b * Sdim + s0 + t) * Edim + e0) =
        pk_fp8x4(y[0], y[1], y[2], y[3]);
  }
}

// ---------------- chunked parallel scan (fp8 u, 4 e/thread) ----------------
// z is kept in u-scaled units (x CSCALE); part2 is linear so unaffected.
__global__ __launch_bounds__(256)
void scan_part1(const u8* __restrict__ u8p, const float* __restrict__ aexp,
                float* __restrict__ zloc) {
  const int c  = blockIdx.x;
  const int b  = blockIdx.y >> 1;
  const int e0 = ((blockIdx.y & 1) * 256 + threadIdx.x) * 4;
  const float4 av = *(const float4*)(aexp + e0);
  const u8* up = u8p + ((size_t)(b * Sdim + c * CL)) * Edim + e0;
  float z0 = 0.f, z1 = 0.f, z2 = 0.f, z3 = 0.f;
  #pragma unroll
  for (int t = 0; t < CL; ++t) {
    const int uv = *(const int*)(up + (size_t)t * Edim);
    z0 = fmaf(av.x, z0, dq8<0>(uv));
    z1 = fmaf(av.y, z1, dq8<1>(uv));
    z2 = fmaf(av.z, z2, dq8<2>(uv));
    z3 = fmaf(av.w, z3, dq8<3>(uv));
  }
  float4 zv = {z0, z1, z2, z3};
  *(float4*)(zloc + ((size_t)b * CH + c) * Edim + e0) = zv;
}

__global__ __launch_bounds__(256)
void scan_part2(const float* __restrict__ aexp, float* __restrict__ zloc) {
  const int idx = blockIdx.x * 256 + threadIdx.x;
  const int b = idx >> 11, e = idx & (Edim - 1);
  float a  = aexp[e];
  float aL = a * a;
  aL = aL * aL; aL = aL * aL; aL = aL * aL; aL = aL * aL;  // a^32
  float* zp = zloc + (size_t)b * CH * Edim + e;
  float pref = 0.f;
  #pragma unroll 4
  for (int c = 0; c < CH; ++c) {
    const float loc = zp[(size_t)c * Edim];
    zp[(size_t)c * Edim] = pref;
    pref = fmaf(aL, pref, loc);
  }
}

// Phase 3: re-scan, gate, write xg fp8.  y*GSCALE = Ce*(z/CSCALE)*sig*GSCALE
__global__ __launch_bounds__(256)
void scan_part3(const u8* __restrict__ u8p, const u8* __restrict__ xpg8,
                const float* __restrict__ aexp, const float* __restrict__ Ce,
                const float* __restrict__ zloc, u8* __restrict__ xg8) {
  const int c  = blockIdx.x;
  const int b  = blockIdx.y >> 1;
  const int e0 = ((blockIdx.y & 1) * 256 + threadIdx.x) * 4;
  const float4 av = *(const float4*)(aexp + e0);
  float4 Cv = *(const float4*)(Ce + e0);
  const float cs = GSCALE / CSCALE;
  Cv.x *= cs; Cv.y *= cs; Cv.z *= cs; Cv.w *= cs;
  float4 zv = *(const float4*)(zloc + ((size_t)b * CH + c) * Edim + e0);
  const u8* up = u8p  + ((size_t)(b * Sdim + c * CL)) * Edim + e0;
  const u8* gp = xpg8 + ((size_t)(b * Sdim + c * CL)) * (2 * Edim) + Edim + e0;
  u8*       op = xg8  + ((size_t)(b * Sdim + c * CL)) * Edim + e0;
  #pragma unroll 4
  for (int t = 0; t < CL; ++t) {
    const int uv = *(const int*)(up + (size_t)t * Edim);
    const int gv = *(const int*)(gp + (size_t)t * (2 * Edim));
    zv.x = fmaf(av.x, zv.x, dq8<0>(uv));
    zv.y = fmaf(av.y, zv.y, dq8<1>(uv));
    zv.z = fmaf(av.z, zv.z, dq8<2>(uv));
    zv.w = fmaf(av.w, zv.w, dq8<3>(uv));
    const float y0 = Cv.x * zv.x * sigmoidf_(dq8<0>(gv) * (1.f / XPSCALE));
    const float y1 = Cv.y * zv.y * sigmoidf_(dq8<1>(gv) * (1.f / XPSCALE));
    const float y2 = Cv.z * zv.z * sigmoidf_(dq8<2>(gv) * (1.f / XPSCALE));
    const float y3 = Cv.w * zv.w * sigmoidf_(dq8<3>(gv) * (1.f / XPSCALE));
    *(int*)(op + (size_t)t * Edim) = pk_fp8x4(y0, y1, y2, y3);
  }
}

extern "C" void kernel_launch(void* const* d_in, const int* in_sizes, int n_in,
                              void* d_out, int out_size, void* d_ws, size_t ws_size,
                              hipStream_t stream) {
  const float* x         = (const float*)d_in[0];
  const float* ln_g      = (const float*)d_in[1];
  const float* ln_b      = (const float*)d_in[2];
  const float* W_in      = (const float*)d_in[3];
  const float* b_in      = (const float*)d_in[4];
  const float* conv_w    = (const float*)d_in[5];
  const float* conv_b    = (const float*)d_in[6];
  const float* Am        = (const float*)d_in[7];
  const float* Bm        = (const float*)d_in[8];
  const float* W_c       = (const float*)d_in[9];
  const float* b_c       = (const float*)d_in[10];
  const float* W_d       = (const float*)d_in[11];
  const float* b_d       = (const float*)d_in[12];
  const float* log_delta = (const float*)d_in[13];
  const float* W_out     = (const float*)d_in[14];
  const float* b_out     = (const float*)d_in[15];
  float* out = (float*)d_out;

  const size_t MiB = 1024 * 1024;
  char* w = (char*)d_ws;
  u8*     wWin8  = (u8*)   (w + 0);             //  4 MiB
  u8*     wWc8   = (u8*)   (w + 4 * MiB);       //  4 MiB
  u8*     wWd8   = (u8*)   (w + 8 * MiB);       //  4 MiB
  u8*     wWout8 = (u8*)   (w + 12 * MiB);      //  2 MiB
  float*  aexp   = (float*)(w + 15 * MiB);
  float*  Ce     = (float*)(w + 15 * MiB + 16384);
  float*  zloc   = (float*)(w + 15 * MiB + 65536);  // 2 MiB
  u8*     xln8   = (u8*)   (w + 18 * MiB);      //  8 MiB (8192x1024)
  u8*     xpg8   = (u8*)   (w + 26 * MiB);      // 32 MiB (8192x4096)
  u8*     xc8    = (u8*)   (w + 58 * MiB);      // 16 MiB
  u8*     c8     = (u8*)   (w + 74 * MiB);      // 16 MiB
  u8*     u8b    = (u8*)   (w + 90 * MiB);      // 16 MiB
  u8*     xg8    = (u8*)   (w + 106 * MiB);     // 16 MiB -> 122 MiB

  const int M = Bdim * Sdim;  // 8192
  const float dsIn  = 1.f / WSCALE;
  const float dsCD  = 1.f / (WSCALE * XCSCALE);
  const float dsOut = 1.f / (WSCALE * GSCALE);

  cvt_fp8_3<<<3 * 4096, 256, 0, stream>>>(W_in, W_c, W_d, wWin8, wWc8, wWd8);
  cvt_fp8<<<(Ddim * Edim) / 1024, 256, 0, stream>>>(W_out, wWout8, Ddim * Edim, WSCALE);
  prep_scalars<<<Edim / 256, 256, 0, stream>>>(log_delta, Am, Bm, aexp, Ce);

  ln_kernel<<<M, 256, 0, stream>>>(x, ln_g, ln_b, xln8);

  // xpg = fp8( (x_ln @ W_in^T + b_in) * XPSCALE )
  gemm_mx<3><<<dim3((2 * Edim) / BN, M / BM), 256, 0, stream>>>(
      xln8, wWin8, b_in, nullptr, nullptr, xpg8, nullptr, dsIn, XPSCALE, M, 2 * Edim, Ddim);

  conv_silu<<<dim3(Bdim * (Sdim / 4), Edim / 1024), 256, 0, stream>>>(xpg8, conv_w, conv_b, xc8);

  // c8 = fp8( (xc @ Wc^T + bc) * CSCALE )
  gemm_mx<3><<<dim3(Edim / BN, M / BM), 256, 0, stream>>>(
      xc8, wWc8, b_c, nullptr, nullptr, c8, nullptr, dsCD, CSCALE, M, Edim, Edim);
  // u8 = fp8( dq(c8) * sigmoid(xc @ Wd^T + bd) )   (= u * CSCALE)
  gemm_mx<2><<<dim3(Edim / BN, M / BM), 256, 0, stream>>>(
      xc8, wWd8, b_d, c8, nullptr, u8b, nullptr, dsCD, 1.f, M, Edim, Edim);

  scan_part1<<<dim3(CH, Bdim * 2), 256, 0, stream>>>(u8b, aexp, zloc);
  scan_part2<<<(Bdim * Edim) / 256, 256, 0, stream>>>(aexp, zloc);
  scan_part3<<<dim3(CH, Bdim * 2), 256, 0, stream>>>(u8b, xpg8, aexp, Ce, zloc, xg8);

  // out = xg @ W_out^T + b_out + x
  gemm_mx<1><<<dim3(Ddim / BN, M / BM), 256, 0, stream>>>(
      xg8, wWout8, b_out, nullptr, x, nullptr, out, dsOut, 1.f, M, Ddim, Edim);

  (void)in_sizes; (void)n_in; (void)out_size; (void)ws_size;
}